// Round 1
// baseline (887.203 us; speedup 1.0000x reference)
//
#include <hip/hip_runtime.h>

#define HD 128   // layer-1 width (H*HID)

// ---------------- CSR build ----------------

__global__ __launch_bounds__(256) void k_zero(int* p, int n) {
  int i = blockIdx.x * 256 + threadIdx.x;
  if (i < n) p[i] = 0;
}

__global__ __launch_bounds__(256) void k_hist(const int* __restrict__ ei, int* __restrict__ cnt, int E) {
  int e = blockIdx.x * 256 + threadIdx.x;
  if (e < E) atomicAdd(&cnt[ei[E + e]], 1);
}

__global__ __launch_bounds__(256) void k_scan1(const int* __restrict__ cnt, int* __restrict__ partial, int n) {
  int i = blockIdx.x * 256 + threadIdx.x;
  int v = (i < n) ? cnt[i] : 0;
  #pragma unroll
  for (int m = 1; m < 64; m <<= 1) v += __shfl_xor(v, m);
  __shared__ int sm[4];
  if ((threadIdx.x & 63) == 0) sm[threadIdx.x >> 6] = v;
  __syncthreads();
  if (threadIdx.x == 0) partial[blockIdx.x] = sm[0] + sm[1] + sm[2] + sm[3];
}

__global__ __launch_bounds__(512) void k_scan2(int* partial, int nb) {
  __shared__ int buf[2][512];
  int t = threadIdx.x;
  int v = (t < nb) ? partial[t] : 0;
  buf[0][t] = v;
  __syncthreads();
  int cur = 0;
  for (int off = 1; off < 512; off <<= 1) {
    int x = buf[cur][t];
    if (t >= off) x += buf[cur][t - off];
    buf[cur ^ 1][t] = x;
    __syncthreads();
    cur ^= 1;
  }
  if (t < nb) partial[t] = buf[cur][t] - v;   // exclusive
}

__global__ __launch_bounds__(256) void k_scan3(const int* __restrict__ cnt, const int* __restrict__ partial,
                                               int* __restrict__ rowptr, int* __restrict__ cursor, int n) {
  __shared__ int buf[2][256];
  int t = threadIdx.x;
  int i = blockIdx.x * 256 + t;
  int v = (i < n) ? cnt[i] : 0;
  buf[0][t] = v;
  __syncthreads();
  int cur = 0;
  for (int off = 1; off < 256; off <<= 1) {
    int x = buf[cur][t];
    if (t >= off) x += buf[cur][t - off];
    buf[cur ^ 1][t] = x;
    __syncthreads();
    cur ^= 1;
  }
  if (i < n) {
    int incl = buf[cur][t];
    int base = partial[blockIdx.x];
    int rp = base + incl - v;
    rowptr[i] = rp;
    cursor[i] = rp;
    if (i == n - 1) rowptr[n] = base + incl;
  }
}

__global__ __launch_bounds__(256) void k_scatter(const int* __restrict__ ei, int* __restrict__ cursor,
                                                 int* __restrict__ ssrc, int E) {
  int e = blockIdx.x * 256 + threadIdx.x;
  if (e < E) {
    int dst = ei[E + e];
    int pos = atomicAdd(&cursor[dst], 1);
    ssrc[pos] = ei[e];
  }
}

// ---------------- fp32 tiled GEMM, K=128 fixed ----------------
// C[M x P] = A[M x 128] @ W[128 x P] + bias, 64x64 tile per block.

__global__ __launch_bounds__(256) void k_gemm128(
    const float* __restrict__ A, const float* __restrict__ W,
    const float* __restrict__ bias, float* __restrict__ C, int M, int P) {
  __shared__ float As[128 * 64];   // [k][row]
  __shared__ float Ws[128 * 64];   // [k][col]
  int t = threadIdx.x;
  int m0 = blockIdx.x * 64;
  int c0 = blockIdx.y * 64;
  #pragma unroll
  for (int it = 0; it < 8; ++it) {
    int idx = t + it * 256;            // 2048 float4s: [64 rows][32 kq]
    int r = idx >> 5, kq = idx & 31;
    float4 f = make_float4(0.f, 0.f, 0.f, 0.f);
    int m = m0 + r;
    if (m < M) f = *(const float4*)&A[(size_t)m * 128 + kq * 4];
    As[(kq * 4 + 0) * 64 + r] = f.x;
    As[(kq * 4 + 1) * 64 + r] = f.y;
    As[(kq * 4 + 2) * 64 + r] = f.z;
    As[(kq * 4 + 3) * 64 + r] = f.w;
  }
  #pragma unroll
  for (int it = 0; it < 8; ++it) {
    int idx = t + it * 256;            // 2048 float4s: [128 k][16 cq]
    int k = idx >> 4, cq = idx & 15;
    float4 f = *(const float4*)&W[(size_t)k * P + c0 + cq * 4];
    *(float4*)&Ws[k * 64 + cq * 4] = f;
  }
  __syncthreads();
  int ty = t >> 4, tx = t & 15;
  float acc[4][4] = {};
  #pragma unroll 8
  for (int k = 0; k < 128; ++k) {
    float4 a = *(const float4*)&As[k * 64 + ty * 4];
    float4 w = *(const float4*)&Ws[k * 64 + tx * 4];
    float av[4] = {a.x, a.y, a.z, a.w};
    float wv[4] = {w.x, w.y, w.z, w.w};
    #pragma unroll
    for (int i2 = 0; i2 < 4; ++i2)
      #pragma unroll
      for (int j2 = 0; j2 < 4; ++j2)
        acc[i2][j2] += av[i2] * wv[j2];
  }
  float4 bv = *(const float4*)&bias[c0 + tx * 4];
  float bb[4] = {bv.x, bv.y, bv.z, bv.w};
  #pragma unroll
  for (int i2 = 0; i2 < 4; ++i2) {
    int m = m0 + ty * 4 + i2;
    if (m < M) {
      float4 o = make_float4(acc[i2][0] + bb[0], acc[i2][1] + bb[1],
                             acc[i2][2] + bb[2], acc[i2][3] + bb[3]);
      *(float4*)&C[(size_t)m * P + c0 + tx * 4] = o;
    }
  }
}

// ---------------- layer-1 fused: attention + aggregate + LN + res + ELU ----------------
// one wave per dst node; 128 feats = float2 per lane; head = lane>>3.
// exp without max-subtraction: |logit| <= ~1 (0.05-scale weights), ratio identical.

__global__ __launch_bounds__(256) void k_gat1(
    const float* __restrict__ XL, const float* __restrict__ XR,
    const float* __restrict__ RES,
    const float* __restrict__ att, const float* __restrict__ bias1,
    const float* __restrict__ g1, const float* __restrict__ b1,
    const int* __restrict__ rowptr, const int* __restrict__ ssrc,
    float* __restrict__ Hout, int n) {
  int lane = threadIdx.x & 63;
  int i = blockIdx.x * 4 + (threadIdx.x >> 6);
  if (i >= n) return;
  int f = lane * 2;
  const size_t ib = (size_t)i * HD;
  float2 xr = *(const float2*)&XR[ib + f];
  float2 atv = *(const float2*)&att[f];
  float accx = 0.f, accy = 0.f, den = 0.f;
  int e0 = rowptr[i], e1 = rowptr[i + 1];
  for (int e = e0 - 1; e < e1; ++e) {     // e = e0-1 is the implicit self-loop
    int src = (e < e0) ? i : ssrc[e];
    float2 v = *(const float2*)&XL[(size_t)src * HD + f];
    float mx = v.x + xr.x, my = v.y + xr.y;
    mx = mx > 0.f ? mx : 0.2f * mx;
    my = my > 0.f ? my : 0.2f * my;
    float tt = mx * atv.x + my * atv.y;
    tt += __shfl_xor(tt, 1);
    tt += __shfl_xor(tt, 2);
    tt += __shfl_xor(tt, 4);              // all 8 lanes of head hold logit
    float p = __expf(tt);
    accx += p * v.x; accy += p * v.y; den += p;
  }
  float inv = 1.f / (den + 1e-16f);
  float2 bv = *(const float2*)&bias1[f];
  float ox = accx * inv + bv.x, oy = accy * inv + bv.y;
  // LayerNorm over 128
  float s = ox + oy;
  #pragma unroll
  for (int m = 1; m < 64; m <<= 1) s += __shfl_xor(s, m);
  float mu = s * (1.f / 128.f);
  float dx = ox - mu, dy = oy - mu;
  float q = dx * dx + dy * dy;
  #pragma unroll
  for (int m = 1; m < 64; m <<= 1) q += __shfl_xor(q, m);
  float rstd = rsqrtf(q * (1.f / 128.f) + 1e-5f);
  float2 gg = *(const float2*)&g1[f];
  float2 bb = *(const float2*)&b1[f];
  float2 rv = *(const float2*)&RES[ib + f];
  float yx = dx * rstd * gg.x + bb.x + rv.x;
  float yy = dy * rstd * gg.y + bb.y + rv.y;
  yx = yx > 0.f ? yx : __expf(yx) - 1.f;  // ELU
  yy = yy > 0.f ? yy : __expf(yy) - 1.f;
  *(float2*)&Hout[ib + f] = make_float2(yx, yy);
}

// ---------------- pack layer-2 weights: [Wl2|Wr2|res2_W|skip_W] -> 128x64 ----------------

__global__ __launch_bounds__(256) void k_pack(
    const float* __restrict__ Wl2, const float* __restrict__ Wr2,
    const float* __restrict__ resW, const float* __restrict__ skipW,
    const float* __restrict__ bl2, const float* __restrict__ br2,
    const float* __restrict__ resb, const float* __restrict__ skipb,
    float* __restrict__ WB, float* __restrict__ BB) {
  int tid = blockIdx.x * 256 + threadIdx.x;
  if (tid < 8192) {
    int k = tid >> 6, j = tid & 63;
    int sel = j >> 4, cc = j & 15;
    const float* src = sel == 0 ? Wl2 : sel == 1 ? Wr2 : sel == 2 ? resW : skipW;
    WB[tid] = src[k * 16 + cc];
  }
  if (tid < 64) {
    int sel = tid >> 4, cc = tid & 15;
    const float* sb = sel == 0 ? bl2 : sel == 1 ? br2 : sel == 2 ? resb : skipb;
    BB[tid] = sb[cc];
  }
}

// ---------------- layer-2 fused: attention + aggregate + LN + res + ELU + skip + out GEMV ----
// 16 lanes per dst node (4 nodes/wave). XC row: [xl2 | xr2 | res2 | skip].

__global__ __launch_bounds__(256) void k_gat2(
    const float* __restrict__ XC, const float* __restrict__ att2,
    const float* __restrict__ bias2,
    const float* __restrict__ g2, const float* __restrict__ b2,
    const int* __restrict__ rowptr, const int* __restrict__ ssrc,
    const float* __restrict__ outW, const float* __restrict__ outB,
    float* __restrict__ Out, int n) {
  __shared__ float sW[1024];
  __shared__ float sB[64];
  int t = threadIdx.x;
  for (int idx = t; idx < 1024; idx += 256) sW[idx] = outW[idx];
  if (t < 64) sB[t] = outB[t];
  __syncthreads();
  int c = t & 15;
  int i = blockIdx.x * 16 + (t >> 4);
  if (i >= n) return;
  const float* row = &XC[(size_t)i * 64];
  float xl = row[c], xr = row[16 + c], resv = row[32 + c], skipv = row[48 + c];
  float a2 = att2[c];
  float acc = 0.f, den = 0.f;
  int e0 = rowptr[i], e1 = rowptr[i + 1];
  for (int e = e0 - 1; e < e1; ++e) {
    int src = (e < e0) ? i : ssrc[e];
    float v = (e < e0) ? xl : XC[(size_t)src * 64 + c];
    float m = v + xr;
    m = m > 0.f ? m : 0.2f * m;
    float tt = m * a2;
    tt += __shfl_xor(tt, 1);
    tt += __shfl_xor(tt, 2);
    tt += __shfl_xor(tt, 4);
    tt += __shfl_xor(tt, 8);
    float p = __expf(tt);
    acc += p * v; den += p;
  }
  float o = acc / (den + 1e-16f) + bias2[c];
  // LayerNorm over 16
  float s = o;
  #pragma unroll
  for (int m = 1; m < 16; m <<= 1) s += __shfl_xor(s, m);
  float mu = s * (1.f / 16.f);
  float d = o - mu;
  float q = d * d;
  #pragma unroll
  for (int m = 1; m < 16; m <<= 1) q += __shfl_xor(q, m);
  float rstd = rsqrtf(q * (1.f / 16.f) + 1e-5f);
  float y = d * rstd * g2[c] + b2[c] + resv;
  y = y > 0.f ? y : __expf(y) - 1.f;      // ELU
  y += skipv;
  // out = h2 @ out_W + out_b : each lane produces 4 of 64 outputs
  float a0 = sB[c * 4 + 0], a1 = sB[c * 4 + 1], a2o = sB[c * 4 + 2], a3 = sB[c * 4 + 3];
  #pragma unroll
  for (int cc = 0; cc < 16; ++cc) {
    float h = __shfl(y, cc, 16);
    a0 += h * sW[cc * 64 + c * 4 + 0];
    a1 += h * sW[cc * 64 + c * 4 + 1];
    a2o += h * sW[cc * 64 + c * 4 + 2];
    a3 += h * sW[cc * 64 + c * 4 + 3];
  }
  *(float4*)&Out[(size_t)i * 64 + c * 4] = make_float4(a0, a1, a2o, a3);
}

// ---------------- launch ----------------

extern "C" void kernel_launch(void* const* d_in, const int* in_sizes, int n_in,
                              void* d_out, int out_size, void* d_ws, size_t ws_size,
                              hipStream_t stream) {
  const float* x     = (const float*)d_in[0];
  const int*   ei    = (const int*)d_in[1];
  const float* Wl1   = (const float*)d_in[2];
  const float* bl1   = (const float*)d_in[3];
  const float* Wr1   = (const float*)d_in[4];
  const float* br1   = (const float*)d_in[5];
  const float* att1  = (const float*)d_in[6];
  const float* bias1 = (const float*)d_in[7];
  const float* Wl2   = (const float*)d_in[8];
  const float* bl2   = (const float*)d_in[9];
  const float* Wr2   = (const float*)d_in[10];
  const float* br2   = (const float*)d_in[11];
  const float* att2  = (const float*)d_in[12];
  const float* bias2 = (const float*)d_in[13];
  const float* ln1g  = (const float*)d_in[14];
  const float* ln1b  = (const float*)d_in[15];
  const float* ln2g  = (const float*)d_in[16];
  const float* ln2b  = (const float*)d_in[17];
  const float* res1W = (const float*)d_in[18];
  const float* res1b = (const float*)d_in[19];
  const float* res2W = (const float*)d_in[20];
  const float* res2b = (const float*)d_in[21];
  const float* skipW = (const float*)d_in[22];
  const float* skipb = (const float*)d_in[23];
  const float* outW  = (const float*)d_in[24];
  const float* outb  = (const float*)d_in[25];
  int N = in_sizes[0] / 128;
  int E = in_sizes[1] / 2;
  float* out = (float*)d_out;

  // workspace layout (~212 MB): XL1, XR1, RES1, H (N*128 f32 each), then small buffers
  float* XL1  = (float*)d_ws;
  float* XR1  = XL1 + (size_t)N * HD;
  float* RES1 = XR1 + (size_t)N * HD;
  float* Hb   = RES1 + (size_t)N * HD;
  float* XC   = XL1;                      // alias: XL1 dead after k_gat1
  float* WB2  = Hb + (size_t)N * HD;
  float* BB2  = WB2 + 8192;
  int* cnt    = (int*)(BB2 + 64);
  int* cursor = cnt + N;
  int* rowptr = cursor + N;
  int* ssrc   = rowptr + N + 1;
  int* partial = ssrc + E;

  int nbS = (N + 255) / 256;
  int nbE = (E + 255) / 256;

  // CSR build (self-loops handled in-kernel, not stored)
  k_zero<<<nbS, 256, 0, stream>>>(cnt, N);
  k_hist<<<nbE, 256, 0, stream>>>(ei, cnt, E);
  k_scan1<<<nbS, 256, 0, stream>>>(cnt, partial, N);
  k_scan2<<<1, 512, 0, stream>>>(partial, nbS);
  k_scan3<<<nbS, 256, 0, stream>>>(cnt, partial, rowptr, cursor, N);
  k_scatter<<<nbE, 256, 0, stream>>>(ei, cursor, ssrc, E);

  // layer-1 node GEMMs
  dim3 g1g((N + 63) / 64, 2);
  k_gemm128<<<g1g, 256, 0, stream>>>(x, Wl1, bl1, XL1, N, 128);
  k_gemm128<<<g1g, 256, 0, stream>>>(x, Wr1, br1, XR1, N, 128);
  k_gemm128<<<g1g, 256, 0, stream>>>(x, res1W, res1b, RES1, N, 128);

  // layer-1 edge+node fused
  k_gat1<<<(N + 3) / 4, 256, 0, stream>>>(XL1, XR1, RES1, att1, bias1, ln1g, ln1b,
                                          rowptr, ssrc, Hb, N);

  // layer-2: pack weights, one 128->64 GEMM, fused edge+node+output
  k_pack<<<32, 256, 0, stream>>>(Wl2, Wr2, res2W, skipW, bl2, br2, res2b, skipb, WB2, BB2);
  dim3 g2g((N + 63) / 64, 1);
  k_gemm128<<<g2g, 256, 0, stream>>>(Hb, WB2, BB2, XC, N, 64);
  k_gat2<<<(N + 15) / 16, 256, 0, stream>>>(XC, att2, bias2, ln2g, ln2b,
                                            rowptr, ssrc, outW, outb, out, N);
}

// Round 2
// 684.768 us; speedup vs baseline: 1.2956x; 1.2956x over previous
//
#include <hip/hip_runtime.h>

// ---------------- CSR build ----------------

__global__ __launch_bounds__(256) void k_zero(int* p, int n) {
  int i = blockIdx.x * 256 + threadIdx.x;
  if (i < n) p[i] = 0;
}

__global__ __launch_bounds__(256) void k_hist(const int* __restrict__ ei, int* __restrict__ cnt, int E) {
  int e = blockIdx.x * 256 + threadIdx.x;
  if (e < E) atomicAdd(&cnt[ei[E + e]], 1);
}

__global__ __launch_bounds__(256) void k_scan1(const int* __restrict__ cnt, int* __restrict__ partial, int n) {
  int i = blockIdx.x * 256 + threadIdx.x;
  int v = (i < n) ? cnt[i] : 0;
  #pragma unroll
  for (int m = 1; m < 64; m <<= 1) v += __shfl_xor(v, m);
  __shared__ int sm[4];
  if ((threadIdx.x & 63) == 0) sm[threadIdx.x >> 6] = v;
  __syncthreads();
  if (threadIdx.x == 0) partial[blockIdx.x] = sm[0] + sm[1] + sm[2] + sm[3];
}

__global__ __launch_bounds__(512) void k_scan2(int* partial, int nb) {
  __shared__ int buf[2][512];
  int t = threadIdx.x;
  int v = (t < nb) ? partial[t] : 0;
  buf[0][t] = v;
  __syncthreads();
  int cur = 0;
  for (int off = 1; off < 512; off <<= 1) {
    int x = buf[cur][t];
    if (t >= off) x += buf[cur][t - off];
    buf[cur ^ 1][t] = x;
    __syncthreads();
    cur ^= 1;
  }
  if (t < nb) partial[t] = buf[cur][t] - v;   // exclusive
}

__global__ __launch_bounds__(256) void k_scan3(const int* __restrict__ cnt, const int* __restrict__ partial,
                                               int* __restrict__ rowptr, int* __restrict__ cursor, int n) {
  __shared__ int buf[2][256];
  int t = threadIdx.x;
  int i = blockIdx.x * 256 + t;
  int v = (i < n) ? cnt[i] : 0;
  buf[0][t] = v;
  __syncthreads();
  int cur = 0;
  for (int off = 1; off < 256; off <<= 1) {
    int x = buf[cur][t];
    if (t >= off) x += buf[cur][t - off];
    buf[cur ^ 1][t] = x;
    __syncthreads();
    cur ^= 1;
  }
  if (i < n) {
    int incl = buf[cur][t];
    int base = partial[blockIdx.x];
    int rp = base + incl - v;
    rowptr[i] = rp;
    cursor[i] = rp;
    if (i == n - 1) rowptr[n] = base + incl;
  }
}

__global__ __launch_bounds__(256) void k_scatter(const int* __restrict__ ei, int* __restrict__ cursor,
                                                 int* __restrict__ ssrc, int E) {
  int e = blockIdx.x * 256 + threadIdx.x;
  if (e < E) {
    int dst = ei[E + e];
    int pos = atomicAdd(&cursor[dst], 1);
    ssrc[pos] = ei[e];
  }
}

// ---------------- weight packing ----------------
// layer1: W1P[128][384] = [Wl1|Wr1|res1W], B1P[384]
// layer2: W2P[128][64]  = [Wl2|Wr2|res2W|skipW], B2P[64]

__global__ __launch_bounds__(256) void k_pack(
    const float* __restrict__ Wl1, const float* __restrict__ bl1,
    const float* __restrict__ Wr1, const float* __restrict__ br1,
    const float* __restrict__ res1W, const float* __restrict__ res1b,
    const float* __restrict__ Wl2, const float* __restrict__ bl2,
    const float* __restrict__ Wr2, const float* __restrict__ br2,
    const float* __restrict__ res2W, const float* __restrict__ res2b,
    const float* __restrict__ skipW, const float* __restrict__ skipb,
    float* __restrict__ W1P, float* __restrict__ B1P,
    float* __restrict__ W2P, float* __restrict__ B2P) {
  int tid = blockIdx.x * 256 + threadIdx.x;
  if (tid < 49152) {
    int k = tid / 384, j = tid - k * 384;
    int sel = j >> 7, jj = j & 127;
    const float* s = sel == 0 ? Wl1 : sel == 1 ? Wr1 : res1W;
    W1P[tid] = s[k * 128 + jj];
    if (tid < 384) {
      const float* sb = sel == 0 ? bl1 : sel == 1 ? br1 : res1b;
      B1P[tid] = sb[jj];
    }
  } else {
    int u = tid - 49152;
    if (u < 8192) {
      int k = u >> 6, j = u & 63;
      int sel = j >> 4, jj = j & 15;
      const float* s = sel == 0 ? Wl2 : sel == 1 ? Wr2 : sel == 2 ? res2W : skipW;
      W2P[u] = s[k * 16 + jj];
      if (u < 64) {
        const float* sb = sel == 0 ? bl2 : sel == 1 ? br2 : sel == 2 ? res2b : skipb;
        B2P[u] = sb[jj];
      }
    }
  }
}

// ---------------- fp32 tiled GEMM, K=128 fixed, 64x64 tile ----------------
// As stored [k][col] with XOR swizzle: col' = col ^ (((k>>2)&15)<<2).
// Writes: 4-way bank conflict (near-free). Reads: conflict-free ds_read_b128.

__global__ __launch_bounds__(256) void k_gemm128(
    const float* __restrict__ A, const float* __restrict__ W,
    const float* __restrict__ bias, float* __restrict__ C, int M, int P) {
  __shared__ float As[128 * 64];
  __shared__ float Ws[128 * 64];
  int t = threadIdx.x;
  int m0 = blockIdx.x * 64;
  int c0 = blockIdx.y * 64;
  #pragma unroll
  for (int it = 0; it < 8; ++it) {
    int idx = t + it * 256;            // [64 rows][32 kq] float4s
    int r = idx >> 5, kq = idx & 31;
    float4 f = make_float4(0.f, 0.f, 0.f, 0.f);
    int m = m0 + r;
    if (m < M) f = *(const float4*)&A[(size_t)m * 128 + kq * 4];
    int kb = kq * 4;
    int rc = r ^ ((kq & 15) << 2);     // swizzled column
    As[(kb + 0) * 64 + rc] = f.x;
    As[(kb + 1) * 64 + rc] = f.y;
    As[(kb + 2) * 64 + rc] = f.z;
    As[(kb + 3) * 64 + rc] = f.w;
  }
  #pragma unroll
  for (int it = 0; it < 8; ++it) {
    int idx = t + it * 256;            // [128 k][16 cq] float4s
    int k = idx >> 4, cq = idx & 15;
    float4 f = *(const float4*)&W[(size_t)k * P + c0 + cq * 4];
    *(float4*)&Ws[k * 64 + cq * 4] = f;
  }
  __syncthreads();
  int ty = t >> 4, tx = t & 15;
  float acc[4][4] = {};
  #pragma unroll 16
  for (int k = 0; k < 128; ++k) {
    float4 a = *(const float4*)&As[k * 64 + ((ty * 4) ^ (((k >> 2) & 15) << 2))];
    float4 w = *(const float4*)&Ws[k * 64 + tx * 4];
    float av[4] = {a.x, a.y, a.z, a.w};
    float wv[4] = {w.x, w.y, w.z, w.w};
    #pragma unroll
    for (int i2 = 0; i2 < 4; ++i2)
      #pragma unroll
      for (int j2 = 0; j2 < 4; ++j2)
        acc[i2][j2] += av[i2] * wv[j2];
  }
  float4 bv = *(const float4*)&bias[c0 + tx * 4];
  float bb[4] = {bv.x, bv.y, bv.z, bv.w};
  #pragma unroll
  for (int i2 = 0; i2 < 4; ++i2) {
    int m = m0 + ty * 4 + i2;
    if (m < M) {
      float4 o = make_float4(acc[i2][0] + bb[0], acc[i2][1] + bb[1],
                             acc[i2][2] + bb[2], acc[i2][3] + bb[3]);
      *(float4*)&C[(size_t)m * P + c0 + tx * 4] = o;
    }
  }
}

// ---------------- layer-1 fused: attention + aggregate + LN + res + ELU ----------------
// one wave per dst node; X row = [xl(128)|xr(128)|res(128)], stride 384.
// chunk-load 64 src indices coalesced, shfl-broadcast, 4x unrolled gather for MLP.

#define EDGE1(v)                                            \
  {                                                         \
    float mx = (v).x + xr.x, my = (v).y + xr.y;             \
    mx = mx > 0.f ? mx : 0.2f * mx;                         \
    my = my > 0.f ? my : 0.2f * my;                         \
    float tt = mx * atv.x + my * atv.y;                     \
    tt += __shfl_xor(tt, 1);                                \
    tt += __shfl_xor(tt, 2);                                \
    tt += __shfl_xor(tt, 4);                                \
    float p = __expf(tt);                                   \
    accx += p * (v).x; accy += p * (v).y; den += p;         \
  }

__global__ __launch_bounds__(256) void k_gat1(
    const float* __restrict__ X,
    const float* __restrict__ att, const float* __restrict__ bias1,
    const float* __restrict__ g1, const float* __restrict__ b1,
    const int* __restrict__ rowptr, const int* __restrict__ ssrc,
    float* __restrict__ Hout, int n) {
  int lane = threadIdx.x & 63;
  int i = blockIdx.x * 4 + (threadIdx.x >> 6);
  if (i >= n) return;
  int f = lane * 2;
  const float* rowi = &X[(size_t)i * 384];
  float2 xl_self = *(const float2*)&rowi[f];
  float2 xr = *(const float2*)&rowi[128 + f];
  float2 atv = *(const float2*)&att[f];
  float accx = 0.f, accy = 0.f, den = 0.f;
  EDGE1(xl_self);                              // implicit self-loop
  int e0 = rowptr[i], e1 = rowptr[i + 1];
  for (int base = e0; base < e1; base += 64) {
    int cnt = e1 - base; if (cnt > 64) cnt = 64;
    int sidx = (lane < cnt) ? ssrc[base + lane] : 0;   // coalesced 256B
    int j = 0;
    for (; j + 4 <= cnt; j += 4) {
      int s0 = __shfl(sidx, j);
      int s1 = __shfl(sidx, j + 1);
      int s2 = __shfl(sidx, j + 2);
      int s3 = __shfl(sidx, j + 3);
      float2 v0 = *(const float2*)&X[(size_t)s0 * 384 + f];
      float2 v1 = *(const float2*)&X[(size_t)s1 * 384 + f];
      float2 v2 = *(const float2*)&X[(size_t)s2 * 384 + f];
      float2 v3 = *(const float2*)&X[(size_t)s3 * 384 + f];
      EDGE1(v0); EDGE1(v1); EDGE1(v2); EDGE1(v3);
    }
    for (; j < cnt; ++j) {
      int s = __shfl(sidx, j);
      float2 v = *(const float2*)&X[(size_t)s * 384 + f];
      EDGE1(v);
    }
  }
  float inv = 1.f / (den + 1e-16f);
  float2 bv = *(const float2*)&bias1[f];
  float ox = accx * inv + bv.x, oy = accy * inv + bv.y;
  float s = ox + oy;
  #pragma unroll
  for (int m = 1; m < 64; m <<= 1) s += __shfl_xor(s, m);
  float mu = s * (1.f / 128.f);
  float dx = ox - mu, dy = oy - mu;
  float q = dx * dx + dy * dy;
  #pragma unroll
  for (int m = 1; m < 64; m <<= 1) q += __shfl_xor(q, m);
  float rstd = rsqrtf(q * (1.f / 128.f) + 1e-5f);
  float2 gg = *(const float2*)&g1[f];
  float2 bb = *(const float2*)&b1[f];
  float2 rv = *(const float2*)&rowi[256 + f];
  float yx = dx * rstd * gg.x + bb.x + rv.x;
  float yy = dy * rstd * gg.y + bb.y + rv.y;
  yx = yx > 0.f ? yx : __expf(yx) - 1.f;
  yy = yy > 0.f ? yy : __expf(yy) - 1.f;
  *(float2*)&Hout[(size_t)i * 128 + f] = make_float2(yx, yy);
}

// ---------------- layer-2 fused ----------------
// 16 lanes per node (4 nodes/wave). XC row: [xl2|xr2|res2|skip], stride 64.

#define EDGE2(v)                                            \
  {                                                         \
    float m = (v) + xr; m = m > 0.f ? m : 0.2f * m;         \
    float tt = m * a2;                                      \
    tt += __shfl_xor(tt, 1);                                \
    tt += __shfl_xor(tt, 2);                                \
    tt += __shfl_xor(tt, 4);                                \
    tt += __shfl_xor(tt, 8);                                \
    float p = __expf(tt);                                   \
    acc += p * (v); den += p;                               \
  }

__global__ __launch_bounds__(256) void k_gat2(
    const float* __restrict__ XC, const float* __restrict__ att2,
    const float* __restrict__ bias2,
    const float* __restrict__ g2, const float* __restrict__ b2,
    const int* __restrict__ rowptr, const int* __restrict__ ssrc,
    const float* __restrict__ outW, const float* __restrict__ outB,
    float* __restrict__ Out, int n) {
  __shared__ float sW[1024];
  __shared__ float sB[64];
  int t = threadIdx.x;
  for (int idx = t; idx < 1024; idx += 256) sW[idx] = outW[idx];
  if (t < 64) sB[t] = outB[t];
  __syncthreads();
  int c = t & 15;
  int i = blockIdx.x * 16 + (t >> 4);
  if (i >= n) return;
  const float* row = &XC[(size_t)i * 64];
  float xl = row[c], xr = row[16 + c], resv = row[32 + c], skipv = row[48 + c];
  float a2 = att2[c];
  float acc = 0.f, den = 0.f;
  EDGE2(xl);                                   // self-loop
  int e0 = rowptr[i], e1 = rowptr[i + 1];
  for (int base = e0; base < e1; base += 16) {
    int cnt = e1 - base; if (cnt > 16) cnt = 16;
    int sidx = (c < cnt) ? ssrc[base + c] : 0;
    int j = 0;
    for (; j + 4 <= cnt; j += 4) {
      int s0 = __shfl(sidx, j, 16);
      int s1 = __shfl(sidx, j + 1, 16);
      int s2 = __shfl(sidx, j + 2, 16);
      int s3 = __shfl(sidx, j + 3, 16);
      float v0 = XC[(size_t)s0 * 64 + c];
      float v1 = XC[(size_t)s1 * 64 + c];
      float v2 = XC[(size_t)s2 * 64 + c];
      float v3 = XC[(size_t)s3 * 64 + c];
      EDGE2(v0); EDGE2(v1); EDGE2(v2); EDGE2(v3);
    }
    for (; j < cnt; ++j) {
      int s = __shfl(sidx, j, 16);
      float v = XC[(size_t)s * 64 + c];
      EDGE2(v);
    }
  }
  float o = acc / (den + 1e-16f) + bias2[c];
  float s = o;
  #pragma unroll
  for (int m = 1; m < 16; m <<= 1) s += __shfl_xor(s, m);
  float mu = s * (1.f / 16.f);
  float d = o - mu;
  float q = d * d;
  #pragma unroll
  for (int m = 1; m < 16; m <<= 1) q += __shfl_xor(q, m);
  float rstd = rsqrtf(q * (1.f / 16.f) + 1e-5f);
  float y = d * rstd * g2[c] + b2[c] + resv;
  y = y > 0.f ? y : __expf(y) - 1.f;
  y += skipv;
  float a0 = sB[c * 4 + 0], a1 = sB[c * 4 + 1], ao2 = sB[c * 4 + 2], a3 = sB[c * 4 + 3];
  #pragma unroll
  for (int cc = 0; cc < 16; ++cc) {
    float h = __shfl(y, cc, 16);
    a0 += h * sW[cc * 64 + c * 4 + 0];
    a1 += h * sW[cc * 64 + c * 4 + 1];
    ao2 += h * sW[cc * 64 + c * 4 + 2];
    a3 += h * sW[cc * 64 + c * 4 + 3];
  }
  *(float4*)&Out[(size_t)i * 64 + c * 4] = make_float4(a0, a1, ao2, a3);
}

// ---------------- launch ----------------

extern "C" void kernel_launch(void* const* d_in, const int* in_sizes, int n_in,
                              void* d_out, int out_size, void* d_ws, size_t ws_size,
                              hipStream_t stream) {
  const float* x     = (const float*)d_in[0];
  const int*   ei    = (const int*)d_in[1];
  const float* Wl1   = (const float*)d_in[2];
  const float* bl1   = (const float*)d_in[3];
  const float* Wr1   = (const float*)d_in[4];
  const float* br1   = (const float*)d_in[5];
  const float* att1  = (const float*)d_in[6];
  const float* bias1 = (const float*)d_in[7];
  const float* Wl2   = (const float*)d_in[8];
  const float* bl2   = (const float*)d_in[9];
  const float* Wr2   = (const float*)d_in[10];
  const float* br2   = (const float*)d_in[11];
  const float* att2  = (const float*)d_in[12];
  const float* bias2 = (const float*)d_in[13];
  const float* ln1g  = (const float*)d_in[14];
  const float* ln1b  = (const float*)d_in[15];
  const float* ln2g  = (const float*)d_in[16];
  const float* ln2b  = (const float*)d_in[17];
  const float* res1W = (const float*)d_in[18];
  const float* res1b = (const float*)d_in[19];
  const float* res2W = (const float*)d_in[20];
  const float* res2b = (const float*)d_in[21];
  const float* skipW = (const float*)d_in[22];
  const float* skipb = (const float*)d_in[23];
  const float* outW  = (const float*)d_in[24];
  const float* outb  = (const float*)d_in[25];
  int N = in_sizes[0] / 128;
  int E = in_sizes[1] / 2;
  float* out = (float*)d_out;

  // workspace layout
  float* XLRR = (float*)d_ws;                    // N*384: [xl|xr|res]
  float* Hb   = XLRR + (size_t)N * 384;          // N*128
  float* XC   = XLRR;                            // alias: XLRR dead after k_gat1
  float* W1P  = Hb + (size_t)N * 128;            // 49152
  float* B1P  = W1P + 49152;                     // 384
  float* W2P  = B1P + 384;                       // 8192
  float* B2P  = W2P + 8192;                      // 64
  int* cnt    = (int*)(B2P + 64);
  int* cursor = cnt + N;
  int* rowptr = cursor + N;
  int* ssrc   = rowptr + N + 1;
  int* partial = ssrc + E;

  int nbS = (N + 255) / 256;
  int nbE = (E + 255) / 256;

  // weight packing (independent of CSR)
  k_pack<<<224, 256, 0, stream>>>(Wl1, bl1, Wr1, br1, res1W, res1b,
                                  Wl2, bl2, Wr2, br2, res2W, res2b, skipW, skipb,
                                  W1P, B1P, W2P, B2P);

  // CSR build (self-loops handled in-kernel, not stored)
  k_zero<<<nbS, 256, 0, stream>>>(cnt, N);
  k_hist<<<nbE, 256, 0, stream>>>(ei, cnt, E);
  k_scan1<<<nbS, 256, 0, stream>>>(cnt, partial, N);
  k_scan2<<<1, 512, 0, stream>>>(partial, nbS);
  k_scan3<<<nbS, 256, 0, stream>>>(cnt, partial, rowptr, cursor, N);
  k_scatter<<<nbE, 256, 0, stream>>>(ei, cursor, ssrc, E);

  // layer-1 node GEMM (fused xl|xr|res), P=384
  dim3 g1g((N + 63) / 64, 6);
  k_gemm128<<<g1g, 256, 0, stream>>>(x, W1P, B1P, XLRR, N, 384);

  // layer-1 edge+node fused
  k_gat1<<<(N + 3) / 4, 256, 0, stream>>>(XLRR, att1, bias1, ln1g, ln1b,
                                          rowptr, ssrc, Hb, N);

  // layer-2: one 128->64 GEMM, fused edge+node+output
  dim3 g2g((N + 63) / 64, 1);
  k_gemm128<<<g2g, 256, 0, stream>>>(Hb, W2P, B2P, XC, N, 64);
  k_gat2<<<(N + 15) / 16, 256, 0, stream>>>(XC, att2, bias2, ln2g, ln2b,
                                            rowptr, ssrc, outW, outb, out, N);
}

// Round 3
// 550.191 us; speedup vs baseline: 1.6125x; 1.2446x over previous
//
#include <hip/hip_runtime.h>

typedef __attribute__((ext_vector_type(8))) short bf16x8;
typedef __attribute__((ext_vector_type(4))) float f32x4;

__device__ __forceinline__ float bf2f(ushort u) {
  union { uint i; float f; } v; v.i = ((uint)u) << 16; return v.f;
}
__device__ __forceinline__ ushort f2bf(float f) {
  union { float f; uint i; } v; v.f = f;
  uint r = (v.i + 0x7FFFu + ((v.i >> 16) & 1u)) >> 16;
  return (ushort)r;
}

// ---------------- CSR build ----------------

__global__ __launch_bounds__(256) void k_zero(int* p, int n) {
  int i = blockIdx.x * 256 + threadIdx.x;
  if (i < n) p[i] = 0;
}

__global__ __launch_bounds__(256) void k_hist(const int* __restrict__ ei, int* __restrict__ cnt, int E) {
  int e = blockIdx.x * 256 + threadIdx.x;
  if (e < E) atomicAdd(&cnt[ei[E + e]], 1);
}

__global__ __launch_bounds__(256) void k_scan1(const int* __restrict__ cnt, int* __restrict__ partial, int n) {
  int i = blockIdx.x * 256 + threadIdx.x;
  int v = (i < n) ? cnt[i] : 0;
  #pragma unroll
  for (int m = 1; m < 64; m <<= 1) v += __shfl_xor(v, m);
  __shared__ int sm[4];
  if ((threadIdx.x & 63) == 0) sm[threadIdx.x >> 6] = v;
  __syncthreads();
  if (threadIdx.x == 0) partial[blockIdx.x] = sm[0] + sm[1] + sm[2] + sm[3];
}

__global__ __launch_bounds__(512) void k_scan2(int* partial, int nb) {
  __shared__ int buf[2][512];
  int t = threadIdx.x;
  int v = (t < nb) ? partial[t] : 0;
  buf[0][t] = v;
  __syncthreads();
  int cur = 0;
  for (int off = 1; off < 512; off <<= 1) {
    int x = buf[cur][t];
    if (t >= off) x += buf[cur][t - off];
    buf[cur ^ 1][t] = x;
    __syncthreads();
    cur ^= 1;
  }
  if (t < nb) partial[t] = buf[cur][t] - v;   // exclusive
}

__global__ __launch_bounds__(256) void k_scan3(const int* __restrict__ cnt, const int* __restrict__ partial,
                                               int* __restrict__ rowptr, int* __restrict__ cursor, int n) {
  __shared__ int buf[2][256];
  int t = threadIdx.x;
  int i = blockIdx.x * 256 + t;
  int v = (i < n) ? cnt[i] : 0;
  buf[0][t] = v;
  __syncthreads();
  int cur = 0;
  for (int off = 1; off < 256; off <<= 1) {
    int x = buf[cur][t];
    if (t >= off) x += buf[cur][t - off];
    buf[cur ^ 1][t] = x;
    __syncthreads();
    cur ^= 1;
  }
  if (i < n) {
    int incl = buf[cur][t];
    int base = partial[blockIdx.x];
    int rp = base + incl - v;
    rowptr[i] = rp;
    cursor[i] = rp;
    if (i == n - 1) rowptr[n] = base + incl;
  }
}

__global__ __launch_bounds__(256) void k_scatter(const int* __restrict__ ei, int* __restrict__ cursor,
                                                 int* __restrict__ ssrc, int E) {
  int e = blockIdx.x * 256 + threadIdx.x;
  if (e < E) {
    int dst = ei[E + e];
    int pos = atomicAdd(&cursor[dst], 1);
    ssrc[pos] = ei[e];
  }
}

// ---------------- x (fp32 row-major) -> bf16 A-fragment order ----------------
// AF[((m>>4)*4 + ktile)*64 + (m&15) + ((k8&3)<<4)] is a 16B slot of 8 bf16
// holding x[m][k8*8 .. k8*8+7], matching mfma_16x16x32_bf16 A-operand layout.

__global__ __launch_bounds__(256) void k_conv(const float* __restrict__ x, ushort* __restrict__ AF, int total) {
  int t = blockIdx.x * 256 + threadIdx.x;    // chunk: m = t>>4, k8 = t&15
  if (t >= total) return;
  int m = t >> 4, k8 = t & 15;
  const float* src = x + (size_t)m * 128 + k8 * 8;
  float4 f0 = *(const float4*)src;
  float4 f1 = *(const float4*)(src + 4);
  uint4 o;
  o.x = f2bf(f0.x) | ((uint)f2bf(f0.y) << 16);
  o.y = f2bf(f0.z) | ((uint)f2bf(f0.w) << 16);
  o.z = f2bf(f1.x) | ((uint)f2bf(f1.y) << 16);
  o.w = f2bf(f1.z) | ((uint)f2bf(f1.w) << 16);
  size_t off = ((size_t)(((m >> 4) * 4 + (k8 >> 2)) * 64) + (m & 15) + ((k8 & 3) << 4)) * 8;
  *(uint4*)(AF + off) = o;
}

// ---------------- weight packing into B-fragment order ----------------
// WF[((ct*4 + ktile)*64 + l)*8 + j] = W[k = ktile*32+(l>>4)*8+j][n = ct*16+(l&15)]
// layer1 W = [Wl1|Wr1|res1W] (P=384), layer2 W = [Wl2|Wr2|res2W|skipW] (P=64).

__global__ __launch_bounds__(256) void k_pack(
    const float* __restrict__ Wl1, const float* __restrict__ bl1,
    const float* __restrict__ Wr1, const float* __restrict__ br1,
    const float* __restrict__ res1W, const float* __restrict__ res1b,
    const float* __restrict__ Wl2, const float* __restrict__ bl2,
    const float* __restrict__ Wr2, const float* __restrict__ br2,
    const float* __restrict__ res2W, const float* __restrict__ res2b,
    const float* __restrict__ skipW, const float* __restrict__ skipb,
    ushort* __restrict__ W1F, float* __restrict__ B1P,
    ushort* __restrict__ W2F, float* __restrict__ B2P) {
  int tid = blockIdx.x * 256 + threadIdx.x;
  if (tid < 49152) {                       // layer-1 weights
    int j = tid & 7, l = (tid >> 3) & 63, ktile = (tid >> 9) & 3, ct = tid >> 11;
    int k = ktile * 32 + ((l >> 4) << 3) + j;
    int n = ct * 16 + (l & 15);
    int sel = n >> 7, jj = n & 127;
    const float* s = sel == 0 ? Wl1 : sel == 1 ? Wr1 : res1W;
    W1F[tid] = f2bf(s[k * 128 + jj]);
  } else if (tid < 57344) {                // layer-2 weights
    int u = tid - 49152;
    int j = u & 7, l = (u >> 3) & 63, ktile = (u >> 9) & 3, ct = u >> 11;
    int k = ktile * 32 + ((l >> 4) << 3) + j;
    int n = ct * 16 + (l & 15);
    int sel = n >> 4, jj = n & 15;
    const float* s = sel == 0 ? Wl2 : sel == 1 ? Wr2 : sel == 2 ? res2W : skipW;
    W2F[u] = f2bf(s[k * 16 + jj]);
  } else if (tid < 57728) {                // layer-1 bias (384)
    int n = tid - 57344;
    int sel = n >> 7, jj = n & 127;
    const float* sb = sel == 0 ? bl1 : sel == 1 ? br1 : res1b;
    B1P[n] = sb[jj];
  } else if (tid < 57792) {                // layer-2 bias (64)
    int n = tid - 57728;
    int sel = n >> 4, jj = n & 15;
    const float* sb = sel == 0 ? bl2 : sel == 1 ? br2 : sel == 2 ? res2b : skipb;
    B2P[n] = sb[jj];
  }
}

// ---------------- MFMA GEMM: C[M x P](bf16) = A[M x 128](frag) @ W(frag) + bias ----
// No LDS, no barriers: both operands pre-swizzled to fragment order in global.
// Block = 4 waves; wave w -> cols [blockIdx.y*64 + w*16), 64 rows.

__global__ __launch_bounds__(256) void k_mfma(
    const ushort* __restrict__ AF, const ushort* __restrict__ WF,
    const float* __restrict__ bias, ushort* __restrict__ C, int M, int P) {
  int w = threadIdx.x >> 6, l = threadIdx.x & 63;
  int m0 = blockIdx.x * 64;
  int c0 = blockIdx.y * 64 + w * 16;
  int ct = c0 >> 4;
  f32x4 acc[4] = {};
  #pragma unroll
  for (int kt = 0; kt < 4; ++kt) {
    bf16x8 b = *(const bf16x8*)(WF + ((size_t)((ct * 4 + kt) * 64 + l)) * 8);
    #pragma unroll
    for (int rt = 0; rt < 4; ++rt) {
      bf16x8 a = *(const bf16x8*)(AF + ((size_t)((blockIdx.x * 16 + rt * 4 + kt) * 64 + l)) * 8);
      acc[rt] = __builtin_amdgcn_mfma_f32_16x16x32_bf16(a, b, acc[rt], 0, 0, 0);
    }
  }
  int col = c0 + (l & 15);
  float bv = bias[col];
  int rbase = m0 + ((l >> 4) << 2);
  #pragma unroll
  for (int rt = 0; rt < 4; ++rt) {
    #pragma unroll
    for (int r = 0; r < 4; ++r) {
      int m = rbase + rt * 16 + r;
      if (m < M) C[(size_t)m * P + col] = f2bf(acc[rt][r] + bv);
    }
  }
}

// ---------------- layer-1 fused: attention + aggregate + LN + res + ELU ----------------
// one wave per dst node; X row = [xl(128)|xr(128)|res(128)] bf16, stride 384.
// Output written directly in A-fragment order for GEMM2.

__device__ __forceinline__ float2 ld2bf(const ushort* p) {
  uint u = *(const uint*)p;
  return make_float2(bf2f((ushort)u), bf2f((ushort)(u >> 16)));
}

#define EDGE1(v)                                            \
  {                                                         \
    float mx = (v).x + xr.x, my = (v).y + xr.y;             \
    mx = mx > 0.f ? mx : 0.2f * mx;                         \
    my = my > 0.f ? my : 0.2f * my;                         \
    float tt = mx * atv.x + my * atv.y;                     \
    tt += __shfl_xor(tt, 1);                                \
    tt += __shfl_xor(tt, 2);                                \
    tt += __shfl_xor(tt, 4);                                \
    float p = __expf(tt);                                   \
    accx += p * (v).x; accy += p * (v).y; den += p;         \
  }

__global__ __launch_bounds__(256) void k_gat1(
    const ushort* __restrict__ X,
    const float* __restrict__ att, const float* __restrict__ bias1,
    const float* __restrict__ g1, const float* __restrict__ b1,
    const int* __restrict__ rowptr, const int* __restrict__ ssrc,
    ushort* __restrict__ HF, int n) {
  int lane = threadIdx.x & 63;
  int i = blockIdx.x * 4 + (threadIdx.x >> 6);
  if (i >= n) return;
  int f = lane * 2;
  const ushort* rowi = X + (size_t)i * 384;
  float2 xl_self = ld2bf(rowi + f);
  float2 xr = ld2bf(rowi + 128 + f);
  float2 atv = *(const float2*)&att[f];
  float accx = 0.f, accy = 0.f, den = 0.f;
  EDGE1(xl_self);                              // implicit self-loop
  int e0 = rowptr[i], e1 = rowptr[i + 1];
  for (int base = e0; base < e1; base += 64) {
    int cnt = e1 - base; if (cnt > 64) cnt = 64;
    int sidx = (lane < cnt) ? ssrc[base + lane] : 0;   // coalesced 256B
    int j = 0;
    for (; j + 4 <= cnt; j += 4) {
      int s0 = __shfl(sidx, j);
      int s1 = __shfl(sidx, j + 1);
      int s2 = __shfl(sidx, j + 2);
      int s3 = __shfl(sidx, j + 3);
      float2 v0 = ld2bf(X + (size_t)s0 * 384 + f);
      float2 v1 = ld2bf(X + (size_t)s1 * 384 + f);
      float2 v2 = ld2bf(X + (size_t)s2 * 384 + f);
      float2 v3 = ld2bf(X + (size_t)s3 * 384 + f);
      EDGE1(v0); EDGE1(v1); EDGE1(v2); EDGE1(v3);
    }
    for (; j < cnt; ++j) {
      int s = __shfl(sidx, j);
      float2 v = ld2bf(X + (size_t)s * 384 + f);
      EDGE1(v);
    }
  }
  float inv = 1.f / (den + 1e-16f);
  float2 bv = *(const float2*)&bias1[f];
  float ox = accx * inv + bv.x, oy = accy * inv + bv.y;
  float s = ox + oy;
  #pragma unroll
  for (int m = 1; m < 64; m <<= 1) s += __shfl_xor(s, m);
  float mu = s * (1.f / 128.f);
  float dx = ox - mu, dy = oy - mu;
  float q = dx * dx + dy * dy;
  #pragma unroll
  for (int m = 1; m < 64; m <<= 1) q += __shfl_xor(q, m);
  float rstd = rsqrtf(q * (1.f / 128.f) + 1e-5f);
  float2 gg = *(const float2*)&g1[f];
  float2 bb = *(const float2*)&b1[f];
  float2 rv = ld2bf(rowi + 256 + f);
  float yx = dx * rstd * gg.x + bb.x + rv.x;
  float yy = dy * rstd * gg.y + bb.y + rv.y;
  yx = yx > 0.f ? yx : __expf(yx) - 1.f;
  yy = yy > 0.f ? yy : __expf(yy) - 1.f;
  // write features k=2*lane, 2*lane+1 in A-fragment order:
  // slot = ((i>>4)*4 + (lane>>4))*64 + (i&15) + ((lane>>2)&3)*16, j = 2*(lane&3)
  size_t off = (((size_t)(i >> 4) * 4 + (lane >> 4)) * 64 + (i & 15) + ((lane >> 2) & 3) * 16) * 8
               + 2 * (lane & 3);
  *(uint*)(HF + off) = (uint)f2bf(yx) | ((uint)f2bf(yy) << 16);
}

// ---------------- layer-2 fused ----------------
// 16 lanes per node (4 nodes/wave). XC row (bf16): [xl2|xr2|res2|skip], stride 64.

#define EDGE2(v)                                            \
  {                                                         \
    float m = (v) + xr; m = m > 0.f ? m : 0.2f * m;         \
    float tt = m * a2;                                      \
    tt += __shfl_xor(tt, 1);                                \
    tt += __shfl_xor(tt, 2);                                \
    tt += __shfl_xor(tt, 4);                                \
    tt += __shfl_xor(tt, 8);                                \
    float p = __expf(tt);                                   \
    acc += p * (v); den += p;                               \
  }

__global__ __launch_bounds__(256) void k_gat2(
    const ushort* __restrict__ XC, const float* __restrict__ att2,
    const float* __restrict__ bias2,
    const float* __restrict__ g2, const float* __restrict__ b2,
    const int* __restrict__ rowptr, const int* __restrict__ ssrc,
    const float* __restrict__ outW, const float* __restrict__ outB,
    float* __restrict__ Out, int n) {
  __shared__ float sW[1024];
  __shared__ float sB[64];
  int t = threadIdx.x;
  for (int idx = t; idx < 1024; idx += 256) sW[idx] = outW[idx];
  if (t < 64) sB[t] = outB[t];
  __syncthreads();
  int c = t & 15;
  int i = blockIdx.x * 16 + (t >> 4);
  if (i >= n) return;
  const ushort* row = XC + (size_t)i * 64;
  float xl = bf2f(row[c]), xr = bf2f(row[16 + c]);
  float resv = bf2f(row[32 + c]), skipv = bf2f(row[48 + c]);
  float a2 = att2[c];
  float acc = 0.f, den = 0.f;
  EDGE2(xl);                                   // self-loop
  int e0 = rowptr[i], e1 = rowptr[i + 1];
  for (int base = e0; base < e1; base += 16) {
    int cnt = e1 - base; if (cnt > 16) cnt = 16;
    int sidx = (c < cnt) ? ssrc[base + c] : 0;
    int j = 0;
    for (; j + 4 <= cnt; j += 4) {
      int s0 = __shfl(sidx, j, 16);
      int s1 = __shfl(sidx, j + 1, 16);
      int s2 = __shfl(sidx, j + 2, 16);
      int s3 = __shfl(sidx, j + 3, 16);
      float v0 = bf2f(XC[(size_t)s0 * 64 + c]);
      float v1 = bf2f(XC[(size_t)s1 * 64 + c]);
      float v2 = bf2f(XC[(size_t)s2 * 64 + c]);
      float v3 = bf2f(XC[(size_t)s3 * 64 + c]);
      EDGE2(v0); EDGE2(v1); EDGE2(v2); EDGE2(v3);
    }
    for (; j < cnt; ++j) {
      int s = __shfl(sidx, j, 16);
      float v = bf2f(XC[(size_t)s * 64 + c]);
      EDGE2(v);
    }
  }
  float o = acc / (den + 1e-16f) + bias2[c];
  float s = o;
  #pragma unroll
  for (int m = 1; m < 16; m <<= 1) s += __shfl_xor(s, m);
  float mu = s * (1.f / 16.f);
  float d = o - mu;
  float q = d * d;
  #pragma unroll
  for (int m = 1; m < 16; m <<= 1) q += __shfl_xor(q, m);
  float rstd = rsqrtf(q * (1.f / 16.f) + 1e-5f);
  float y = d * rstd * g2[c] + b2[c] + resv;
  y = y > 0.f ? y : __expf(y) - 1.f;
  y += skipv;
  float a0 = sB[c * 4 + 0], a1 = sB[c * 4 + 1], ao2 = sB[c * 4 + 2], a3 = sB[c * 4 + 3];
  #pragma unroll
  for (int cc = 0; cc < 16; ++cc) {
    float h = __shfl(y, cc, 16);
    a0 += h * sW[cc * 64 + c * 4 + 0];
    a1 += h * sW[cc * 64 + c * 4 + 1];
    ao2 += h * sW[cc * 64 + c * 4 + 2];
    a3 += h * sW[cc * 64 + c * 4 + 3];
  }
  *(float4*)&Out[(size_t)i * 64 + c * 4] = make_float4(a0, a1, ao2, a3);
}

// ---------------- launch ----------------

extern "C" void kernel_launch(void* const* d_in, const int* in_sizes, int n_in,
                              void* d_out, int out_size, void* d_ws, size_t ws_size,
                              hipStream_t stream) {
  const float* x     = (const float*)d_in[0];
  const int*   ei    = (const int*)d_in[1];
  const float* Wl1   = (const float*)d_in[2];
  const float* bl1   = (const float*)d_in[3];
  const float* Wr1   = (const float*)d_in[4];
  const float* br1   = (const float*)d_in[5];
  const float* att1  = (const float*)d_in[6];
  const float* bias1 = (const float*)d_in[7];
  const float* Wl2   = (const float*)d_in[8];
  const float* bl2   = (const float*)d_in[9];
  const float* Wr2   = (const float*)d_in[10];
  const float* br2   = (const float*)d_in[11];
  const float* att2  = (const float*)d_in[12];
  const float* bias2 = (const float*)d_in[13];
  const float* ln1g  = (const float*)d_in[14];
  const float* ln1b  = (const float*)d_in[15];
  const float* ln2g  = (const float*)d_in[16];
  const float* ln2b  = (const float*)d_in[17];
  const float* res1W = (const float*)d_in[18];
  const float* res1b = (const float*)d_in[19];
  const float* res2W = (const float*)d_in[20];
  const float* res2b = (const float*)d_in[21];
  const float* skipW = (const float*)d_in[22];
  const float* skipb = (const float*)d_in[23];
  const float* outW  = (const float*)d_in[24];
  const float* outb  = (const float*)d_in[25];
  int N = in_sizes[0] / 128;
  int E = in_sizes[1] / 2;
  float* out = (float*)d_out;

  int nblk = (N + 63) / 64;            // 64-row GEMM blocks
  int ngrp = nblk * 4;                 // padded 16-row fragment groups

  // workspace layout (all 16B-aligned)
  ushort* XF   = (ushort*)d_ws;                      // ngrp*4*64*8
  ushort* XLRR = XF + (size_t)ngrp * 2048;           // N*384 bf16
  ushort* HF   = XLRR + (size_t)N * 384;             // ngrp*4*64*8
  ushort* XC   = HF + (size_t)ngrp * 2048;           // N*64 bf16
  ushort* W1F  = XC + (size_t)N * 64;                // 49152
  ushort* W2F  = W1F + 49152;                        // 8192
  float*  B1P  = (float*)(W2F + 8192);               // 384
  float*  B2P  = B1P + 384;                          // 64
  int* cnt     = (int*)(B2P + 64);
  int* cursor  = cnt + N;
  int* rowptr  = cursor + N;
  int* ssrc    = rowptr + N + 1;
  int* partial = ssrc + E;

  int nbS = (N + 255) / 256;
  int nbE = (E + 255) / 256;

  // weight packing + x conversion (independent of CSR)
  k_pack<<<226, 256, 0, stream>>>(Wl1, bl1, Wr1, br1, res1W, res1b,
                                  Wl2, bl2, Wr2, br2, res2W, res2b, skipW, skipb,
                                  W1F, B1P, W2F, B2P);
  k_conv<<<(N * 16 + 255) / 256, 256, 0, stream>>>(x, XF, N * 16);

  // CSR build (self-loops handled in-kernel, not stored)
  k_zero<<<nbS, 256, 0, stream>>>(cnt, N);
  k_hist<<<nbE, 256, 0, stream>>>(ei, cnt, E);
  k_scan1<<<nbS, 256, 0, stream>>>(cnt, partial, N);
  k_scan2<<<1, 512, 0, stream>>>(partial, nbS);
  k_scan3<<<nbS, 256, 0, stream>>>(cnt, partial, rowptr, cursor, N);
  k_scatter<<<nbE, 256, 0, stream>>>(ei, cursor, ssrc, E);

  // layer-1 node GEMM (fused xl|xr|res), P=384, bf16 MFMA
  dim3 g1g(nblk, 6);
  k_mfma<<<g1g, 256, 0, stream>>>(XF, W1F, B1P, XLRR, N, 384);

  // layer-1 edge+node fused (writes GEMM2 A-fragments directly)
  k_gat1<<<(N + 3) / 4, 256, 0, stream>>>(XLRR, att1, bias1, ln1g, ln1b,
                                          rowptr, ssrc, HF, N);

  // layer-2: one 128->64 GEMM, fused edge+node+output
  dim3 g2g(nblk, 1);
  k_mfma<<<g2g, 256, 0, stream>>>(HF, W2F, B2P, XC, N, 64);
  k_gat2<<<(N + 15) / 16, 256, 0, stream>>>(XC, att2, bias2, ln2g, ln2b,
                                            rowptr, ssrc, outW, outb, out, N);
}

// Round 4
// 506.906 us; speedup vs baseline: 1.7502x; 1.0854x over previous
//
#include <hip/hip_runtime.h>

typedef __attribute__((ext_vector_type(8))) short bf16x8;
typedef __attribute__((ext_vector_type(4))) float f32x4;

__device__ __forceinline__ float bf2f(ushort u) {
  union { uint i; float f; } v; v.i = ((uint)u) << 16; return v.f;
}
__device__ __forceinline__ ushort f2bf(float f) {
  union { float f; uint i; } v; v.f = f;
  uint r = (v.i + 0x7FFFu + ((v.i >> 16) & 1u)) >> 16;
  return (ushort)r;
}

// ---------------- CSR build ----------------

__global__ __launch_bounds__(256) void k_zero(int* p, int n) {
  int i = blockIdx.x * 256 + threadIdx.x;
  if (i < n) p[i] = 0;
}

__global__ __launch_bounds__(256) void k_hist(const int* __restrict__ ei, int* __restrict__ cnt, int E) {
  int e = blockIdx.x * 256 + threadIdx.x;
  if (e < E) atomicAdd(&cnt[ei[E + e]], 1);
}

__global__ __launch_bounds__(256) void k_scan1(const int* __restrict__ cnt, int* __restrict__ partial, int n) {
  int i = blockIdx.x * 256 + threadIdx.x;
  int v = (i < n) ? cnt[i] : 0;
  #pragma unroll
  for (int m = 1; m < 64; m <<= 1) v += __shfl_xor(v, m);
  __shared__ int sm[4];
  if ((threadIdx.x & 63) == 0) sm[threadIdx.x >> 6] = v;
  __syncthreads();
  if (threadIdx.x == 0) partial[blockIdx.x] = sm[0] + sm[1] + sm[2] + sm[3];
}

__global__ __launch_bounds__(512) void k_scan2(int* partial, int nb) {
  __shared__ int buf[2][512];
  int t = threadIdx.x;
  int v = (t < nb) ? partial[t] : 0;
  buf[0][t] = v;
  __syncthreads();
  int cur = 0;
  for (int off = 1; off < 512; off <<= 1) {
    int x = buf[cur][t];
    if (t >= off) x += buf[cur][t - off];
    buf[cur ^ 1][t] = x;
    __syncthreads();
    cur ^= 1;
  }
  if (t < nb) partial[t] = buf[cur][t] - v;   // exclusive
}

__global__ __launch_bounds__(256) void k_scan3(const int* __restrict__ cnt, const int* __restrict__ partial,
                                               int* __restrict__ rowptr, int* __restrict__ cursor, int n) {
  __shared__ int buf[2][256];
  int t = threadIdx.x;
  int i = blockIdx.x * 256 + t;
  int v = (i < n) ? cnt[i] : 0;
  buf[0][t] = v;
  __syncthreads();
  int cur = 0;
  for (int off = 1; off < 256; off <<= 1) {
    int x = buf[cur][t];
    if (t >= off) x += buf[cur][t - off];
    buf[cur ^ 1][t] = x;
    __syncthreads();
    cur ^= 1;
  }
  if (i < n) {
    int incl = buf[cur][t];
    int base = partial[blockIdx.x];
    int rp = base + incl - v;
    rowptr[i] = rp;
    cursor[i] = rp;
    if (i == n - 1) rowptr[n] = base + incl;
  }
}

// sliced scatter: block holds 2048 edges in registers, sweeps 8192-node dst
// slices so the active ssrc write window stays L2-resident (kills the 16x
// write amplification seen in R3: WRITE_SIZE 106MB for a 6.4MB array).
__global__ __launch_bounds__(256) void k_scatter(const int* __restrict__ ei, int* __restrict__ cursor,
                                                 int* __restrict__ ssrc, int E, int NS) {
  int t = threadIdx.x;
  int base = blockIdx.x * 2048;
  int src[8], dst[8];
  #pragma unroll
  for (int j = 0; j < 8; ++j) {
    int idx = base + j * 256 + t;
    bool ok = idx < E;
    src[j] = ok ? ei[idx] : 0;
    dst[j] = ok ? ei[E + idx] : -1;     // -1 >> 13 == -1: never matches a slice
  }
  for (int s = 0; s < NS; ++s) {
    #pragma unroll
    for (int j = 0; j < 8; ++j) {
      if ((dst[j] >> 13) == s) {
        int pos = atomicAdd(&cursor[dst[j]], 1);
        ssrc[pos] = src[j];
      }
    }
  }
}

// ---------------- x (fp32 row-major) -> bf16 A-fragment order ----------------
// AF[((m>>4)*4 + ktile)*64 + (m&15) + ((k8&3)<<4)] is a 16B slot of 8 bf16
// holding x[m][k8*8 .. k8*8+7], matching mfma_16x16x32_bf16 A-operand layout.

__global__ __launch_bounds__(256) void k_conv(const float* __restrict__ x, ushort* __restrict__ AF, int total) {
  int t = blockIdx.x * 256 + threadIdx.x;    // chunk: m = t>>4, k8 = t&15
  if (t >= total) return;
  int m = t >> 4, k8 = t & 15;
  const float* src = x + (size_t)m * 128 + k8 * 8;
  float4 f0 = *(const float4*)src;
  float4 f1 = *(const float4*)(src + 4);
  uint4 o;
  o.x = f2bf(f0.x) | ((uint)f2bf(f0.y) << 16);
  o.y = f2bf(f0.z) | ((uint)f2bf(f0.w) << 16);
  o.z = f2bf(f1.x) | ((uint)f2bf(f1.y) << 16);
  o.w = f2bf(f1.z) | ((uint)f2bf(f1.w) << 16);
  size_t off = ((size_t)(((m >> 4) * 4 + (k8 >> 2)) * 64) + (m & 15) + ((k8 & 3) << 4)) * 8;
  *(uint4*)(AF + off) = o;
}

// ---------------- weight packing into B-fragment order ----------------
// WF[((ct*4 + ktile)*64 + l)*8 + j] = W[k = ktile*32+(l>>4)*8+j][n = ct*16+(l&15)]
// layer1 W = [Wl1|Wr1|res1W] (P=384), layer2 W = [Wl2|Wr2|res2W|skipW] (P=64).

__global__ __launch_bounds__(256) void k_pack(
    const float* __restrict__ Wl1, const float* __restrict__ bl1,
    const float* __restrict__ Wr1, const float* __restrict__ br1,
    const float* __restrict__ res1W, const float* __restrict__ res1b,
    const float* __restrict__ Wl2, const float* __restrict__ bl2,
    const float* __restrict__ Wr2, const float* __restrict__ br2,
    const float* __restrict__ res2W, const float* __restrict__ res2b,
    const float* __restrict__ skipW, const float* __restrict__ skipb,
    ushort* __restrict__ W1F, float* __restrict__ B1P,
    ushort* __restrict__ W2F, float* __restrict__ B2P) {
  int tid = blockIdx.x * 256 + threadIdx.x;
  if (tid < 49152) {                       // layer-1 weights
    int j = tid & 7, l = (tid >> 3) & 63, ktile = (tid >> 9) & 3, ct = tid >> 11;
    int k = ktile * 32 + ((l >> 4) << 3) + j;
    int n = ct * 16 + (l & 15);
    int sel = n >> 7, jj = n & 127;
    const float* s = sel == 0 ? Wl1 : sel == 1 ? Wr1 : res1W;
    W1F[tid] = f2bf(s[k * 128 + jj]);
  } else if (tid < 57344) {                // layer-2 weights
    int u = tid - 49152;
    int j = u & 7, l = (u >> 3) & 63, ktile = (u >> 9) & 3, ct = u >> 11;
    int k = ktile * 32 + ((l >> 4) << 3) + j;
    int n = ct * 16 + (l & 15);
    int sel = n >> 4, jj = n & 15;
    const float* s = sel == 0 ? Wl2 : sel == 1 ? Wr2 : sel == 2 ? res2W : skipW;
    W2F[u] = f2bf(s[k * 16 + jj]);
  } else if (tid < 57728) {                // layer-1 bias (384)
    int n = tid - 57344;
    int sel = n >> 7, jj = n & 127;
    const float* sb = sel == 0 ? bl1 : sel == 1 ? br1 : res1b;
    B1P[n] = sb[jj];
  } else if (tid < 57792) {                // layer-2 bias (64)
    int n = tid - 57728;
    int sel = n >> 4, jj = n & 15;
    const float* sb = sel == 0 ? bl2 : sel == 1 ? br2 : sel == 2 ? res2b : skipb;
    B2P[n] = sb[jj];
  }
}

// ---------------- MFMA GEMM: C[M x P](bf16) = A[M x 128](frag) @ W(frag) + bias ----
// No LDS, no barriers: both operands pre-swizzled to fragment order in global.
// Block = 4 waves; wave w -> cols [blockIdx.y*64 + w*16), 64 rows.

__global__ __launch_bounds__(256) void k_mfma(
    const ushort* __restrict__ AF, const ushort* __restrict__ WF,
    const float* __restrict__ bias, ushort* __restrict__ C, int M, int P) {
  int w = threadIdx.x >> 6, l = threadIdx.x & 63;
  int m0 = blockIdx.x * 64;
  int c0 = blockIdx.y * 64 + w * 16;
  int ct = c0 >> 4;
  f32x4 acc[4] = {};
  #pragma unroll
  for (int kt = 0; kt < 4; ++kt) {
    bf16x8 b = *(const bf16x8*)(WF + ((size_t)((ct * 4 + kt) * 64 + l)) * 8);
    #pragma unroll
    for (int rt = 0; rt < 4; ++rt) {
      bf16x8 a = *(const bf16x8*)(AF + ((size_t)((blockIdx.x * 16 + rt * 4 + kt) * 64 + l)) * 8);
      acc[rt] = __builtin_amdgcn_mfma_f32_16x16x32_bf16(a, b, acc[rt], 0, 0, 0);
    }
  }
  int col = c0 + (l & 15);
  float bv = bias[col];
  int rbase = m0 + ((l >> 4) << 2);
  #pragma unroll
  for (int rt = 0; rt < 4; ++rt) {
    #pragma unroll
    for (int r = 0; r < 4; ++r) {
      int m = rbase + rt * 16 + r;
      if (m < M) C[(size_t)m * P + col] = f2bf(acc[rt][r] + bv);
    }
  }
}

// ---------------- layer-1 fused: attention + aggregate + LN + res + ELU ----------------
// one wave per dst node; X row = [xl(128)|xr(128)|res(128)] bf16, stride 384.
// Output written directly in A-fragment order for GEMM2.

__device__ __forceinline__ float2 ld2bf(const ushort* p) {
  uint u = *(const uint*)p;
  return make_float2(bf2f((ushort)u), bf2f((ushort)(u >> 16)));
}

#define EDGE1(v)                                            \
  {                                                         \
    float mx = (v).x + xr.x, my = (v).y + xr.y;             \
    mx = mx > 0.f ? mx : 0.2f * mx;                         \
    my = my > 0.f ? my : 0.2f * my;                         \
    float tt = mx * atv.x + my * atv.y;                     \
    tt += __shfl_xor(tt, 1);                                \
    tt += __shfl_xor(tt, 2);                                \
    tt += __shfl_xor(tt, 4);                                \
    float p = __expf(tt);                                   \
    accx += p * (v).x; accy += p * (v).y; den += p;         \
  }

__global__ __launch_bounds__(256) void k_gat1(
    const ushort* __restrict__ X,
    const float* __restrict__ att, const float* __restrict__ bias1,
    const float* __restrict__ g1, const float* __restrict__ b1,
    const int* __restrict__ rowptr, const int* __restrict__ ssrc,
    ushort* __restrict__ HF, int n) {
  int lane = threadIdx.x & 63;
  int i = blockIdx.x * 4 + (threadIdx.x >> 6);
  if (i >= n) return;
  int f = lane * 2;
  const ushort* rowi = X + (size_t)i * 384;
  float2 xl_self = ld2bf(rowi + f);
  float2 xr = ld2bf(rowi + 128 + f);
  float2 atv = *(const float2*)&att[f];
  float accx = 0.f, accy = 0.f, den = 0.f;
  EDGE1(xl_self);                              // implicit self-loop
  int e0 = rowptr[i], e1 = rowptr[i + 1];
  for (int base = e0; base < e1; base += 64) {
    int cnt = e1 - base; if (cnt > 64) cnt = 64;
    int sidx = (lane < cnt) ? ssrc[base + lane] : 0;   // coalesced 256B
    int j = 0;
    for (; j + 4 <= cnt; j += 4) {
      int s0 = __shfl(sidx, j);
      int s1 = __shfl(sidx, j + 1);
      int s2 = __shfl(sidx, j + 2);
      int s3 = __shfl(sidx, j + 3);
      float2 v0 = ld2bf(X + (size_t)s0 * 384 + f);
      float2 v1 = ld2bf(X + (size_t)s1 * 384 + f);
      float2 v2 = ld2bf(X + (size_t)s2 * 384 + f);
      float2 v3 = ld2bf(X + (size_t)s3 * 384 + f);
      EDGE1(v0); EDGE1(v1); EDGE1(v2); EDGE1(v3);
    }
    for (; j < cnt; ++j) {
      int s = __shfl(sidx, j);
      float2 v = ld2bf(X + (size_t)s * 384 + f);
      EDGE1(v);
    }
  }
  float inv = 1.f / (den + 1e-16f);
  float2 bv = *(const float2*)&bias1[f];
  float ox = accx * inv + bv.x, oy = accy * inv + bv.y;
  float s = ox + oy;
  #pragma unroll
  for (int m = 1; m < 64; m <<= 1) s += __shfl_xor(s, m);
  float mu = s * (1.f / 128.f);
  float dx = ox - mu, dy = oy - mu;
  float q = dx * dx + dy * dy;
  #pragma unroll
  for (int m = 1; m < 64; m <<= 1) q += __shfl_xor(q, m);
  float rstd = rsqrtf(q * (1.f / 128.f) + 1e-5f);
  float2 gg = *(const float2*)&g1[f];
  float2 bb = *(const float2*)&b1[f];
  float2 rv = ld2bf(rowi + 256 + f);
  float yx = dx * rstd * gg.x + bb.x + rv.x;
  float yy = dy * rstd * gg.y + bb.y + rv.y;
  yx = yx > 0.f ? yx : __expf(yx) - 1.f;
  yy = yy > 0.f ? yy : __expf(yy) - 1.f;
  // write features k=2*lane, 2*lane+1 in A-fragment order:
  // slot = ((i>>4)*4 + (lane>>4))*64 + (i&15) + ((lane>>2)&3)*16, j = 2*(lane&3)
  size_t off = (((size_t)(i >> 4) * 4 + (lane >> 4)) * 64 + (i & 15) + ((lane >> 2) & 3) * 16) * 8
               + 2 * (lane & 3);
  *(uint*)(HF + off) = (uint)f2bf(yx) | ((uint)f2bf(yy) << 16);
}

// ---------------- layer-2 fused ----------------
// 16 lanes per node (4 nodes/wave). XC row (bf16): [xl2|xr2|res2|skip], stride 64.

#define EDGE2(v)                                            \
  {                                                         \
    float m = (v) + xr; m = m > 0.f ? m : 0.2f * m;         \
    float tt = m * a2;                                      \
    tt += __shfl_xor(tt, 1);                                \
    tt += __shfl_xor(tt, 2);                                \
    tt += __shfl_xor(tt, 4);                                \
    tt += __shfl_xor(tt, 8);                                \
    float p = __expf(tt);                                   \
    acc += p * (v); den += p;                               \
  }

__global__ __launch_bounds__(256) void k_gat2(
    const ushort* __restrict__ XC, const float* __restrict__ att2,
    const float* __restrict__ bias2,
    const float* __restrict__ g2, const float* __restrict__ b2,
    const int* __restrict__ rowptr, const int* __restrict__ ssrc,
    const float* __restrict__ outW, const float* __restrict__ outB,
    float* __restrict__ Out, int n) {
  __shared__ float sW[1024];
  __shared__ float sB[64];
  int t = threadIdx.x;
  for (int idx = t; idx < 1024; idx += 256) sW[idx] = outW[idx];
  if (t < 64) sB[t] = outB[t];
  __syncthreads();
  int c = t & 15;
  int i = blockIdx.x * 16 + (t >> 4);
  if (i >= n) return;
  const ushort* row = XC + (size_t)i * 64;
  float xl = bf2f(row[c]), xr = bf2f(row[16 + c]);
  float resv = bf2f(row[32 + c]), skipv = bf2f(row[48 + c]);
  float a2 = att2[c];
  float acc = 0.f, den = 0.f;
  EDGE2(xl);                                   // self-loop
  int e0 = rowptr[i], e1 = rowptr[i + 1];
  for (int base = e0; base < e1; base += 16) {
    int cnt = e1 - base; if (cnt > 16) cnt = 16;
    int sidx = (c < cnt) ? ssrc[base + c] : 0;
    int j = 0;
    for (; j + 4 <= cnt; j += 4) {
      int s0 = __shfl(sidx, j, 16);
      int s1 = __shfl(sidx, j + 1, 16);
      int s2 = __shfl(sidx, j + 2, 16);
      int s3 = __shfl(sidx, j + 3, 16);
      float v0 = bf2f(XC[(size_t)s0 * 64 + c]);
      float v1 = bf2f(XC[(size_t)s1 * 64 + c]);
      float v2 = bf2f(XC[(size_t)s2 * 64 + c]);
      float v3 = bf2f(XC[(size_t)s3 * 64 + c]);
      EDGE2(v0); EDGE2(v1); EDGE2(v2); EDGE2(v3);
    }
    for (; j < cnt; ++j) {
      int s = __shfl(sidx, j, 16);
      float v = bf2f(XC[(size_t)s * 64 + c]);
      EDGE2(v);
    }
  }
  float o = acc / (den + 1e-16f) + bias2[c];
  float s = o;
  #pragma unroll
  for (int m = 1; m < 16; m <<= 1) s += __shfl_xor(s, m);
  float mu = s * (1.f / 16.f);
  float d = o - mu;
  float q = d * d;
  #pragma unroll
  for (int m = 1; m < 16; m <<= 1) q += __shfl_xor(q, m);
  float rstd = rsqrtf(q * (1.f / 16.f) + 1e-5f);
  float y = d * rstd * g2[c] + b2[c] + resv;
  y = y > 0.f ? y : __expf(y) - 1.f;
  y += skipv;
  float a0 = sB[c * 4 + 0], a1 = sB[c * 4 + 1], ao2 = sB[c * 4 + 2], a3 = sB[c * 4 + 3];
  #pragma unroll
  for (int cc = 0; cc < 16; ++cc) {
    float h = __shfl(y, cc, 16);
    a0 += h * sW[cc * 64 + c * 4 + 0];
    a1 += h * sW[cc * 64 + c * 4 + 1];
    ao2 += h * sW[cc * 64 + c * 4 + 2];
    a3 += h * sW[cc * 64 + c * 4 + 3];
  }
  *(float4*)&Out[(size_t)i * 64 + c * 4] = make_float4(a0, a1, ao2, a3);
}

// ---------------- launch ----------------

extern "C" void kernel_launch(void* const* d_in, const int* in_sizes, int n_in,
                              void* d_out, int out_size, void* d_ws, size_t ws_size,
                              hipStream_t stream) {
  const float* x     = (const float*)d_in[0];
  const int*   ei    = (const int*)d_in[1];
  const float* Wl1   = (const float*)d_in[2];
  const float* bl1   = (const float*)d_in[3];
  const float* Wr1   = (const float*)d_in[4];
  const float* br1   = (const float*)d_in[5];
  const float* att1  = (const float*)d_in[6];
  const float* bias1 = (const float*)d_in[7];
  const float* Wl2   = (const float*)d_in[8];
  const float* bl2   = (const float*)d_in[9];
  const float* Wr2   = (const float*)d_in[10];
  const float* br2   = (const float*)d_in[11];
  const float* att2  = (const float*)d_in[12];
  const float* bias2 = (const float*)d_in[13];
  const float* ln1g  = (const float*)d_in[14];
  const float* ln1b  = (const float*)d_in[15];
  const float* ln2g  = (const float*)d_in[16];
  const float* ln2b  = (const float*)d_in[17];
  const float* res1W = (const float*)d_in[18];
  const float* res1b = (const float*)d_in[19];
  const float* res2W = (const float*)d_in[20];
  const float* res2b = (const float*)d_in[21];
  const float* skipW = (const float*)d_in[22];
  const float* skipb = (const float*)d_in[23];
  const float* outW  = (const float*)d_in[24];
  const float* outb  = (const float*)d_in[25];
  int N = in_sizes[0] / 128;
  int E = in_sizes[1] / 2;
  float* out = (float*)d_out;

  int nblk = (N + 63) / 64;            // 64-row GEMM blocks
  int ngrp = nblk * 4;                 // padded 16-row fragment groups

  // workspace layout (all 16B-aligned)
  ushort* XF   = (ushort*)d_ws;                      // ngrp*4*64*8
  ushort* XLRR = XF + (size_t)ngrp * 2048;           // N*384 bf16
  ushort* HF   = XLRR + (size_t)N * 384;             // ngrp*4*64*8
  ushort* XC   = HF + (size_t)ngrp * 2048;           // N*64 bf16
  ushort* W1F  = XC + (size_t)N * 64;                // 49152
  ushort* W2F  = W1F + 49152;                        // 8192
  float*  B1P  = (float*)(W2F + 8192);               // 384
  float*  B2P  = B1P + 384;                          // 64
  int* cnt     = (int*)(B2P + 64);
  int* cursor  = cnt + N;
  int* rowptr  = cursor + N;
  int* ssrc    = rowptr + N + 1;
  int* partial = ssrc + E;

  int nbS = (N + 255) / 256;
  int nbE = (E + 255) / 256;
  int NS = ((N - 1) >> 13) + 1;        // dst slices of 8192 nodes

  // weight packing + x conversion (independent of CSR)
  k_pack<<<226, 256, 0, stream>>>(Wl1, bl1, Wr1, br1, res1W, res1b,
                                  Wl2, bl2, Wr2, br2, res2W, res2b, skipW, skipb,
                                  W1F, B1P, W2F, B2P);
  k_conv<<<(N * 16 + 255) / 256, 256, 0, stream>>>(x, XF, N * 16);

  // CSR build (self-loops handled in-kernel, not stored)
  k_zero<<<nbS, 256, 0, stream>>>(cnt, N);
  k_hist<<<nbE, 256, 0, stream>>>(ei, cnt, E);
  k_scan1<<<nbS, 256, 0, stream>>>(cnt, partial, N);
  k_scan2<<<1, 512, 0, stream>>>(partial, nbS);
  k_scan3<<<nbS, 256, 0, stream>>>(cnt, partial, rowptr, cursor, N);
  k_scatter<<<(E + 2047) / 2048, 256, 0, stream>>>(ei, cursor, ssrc, E, NS);

  // layer-1 node GEMM (fused xl|xr|res), P=384, bf16 MFMA
  dim3 g1g(nblk, 6);
  k_mfma<<<g1g, 256, 0, stream>>>(XF, W1F, B1P, XLRR, N, 384);

  // layer-1 edge+node fused (writes GEMM2 A-fragments directly)
  k_gat1<<<(N + 3) / 4, 256, 0, stream>>>(XLRR, att1, bias1, ln1g, ln1b,
                                          rowptr, ssrc, HF, N);

  // layer-2: one 128->64 GEMM, fused edge+node+output
  dim3 g2g(nblk, 1);
  k_mfma<<<g2g, 256, 0, stream>>>(HF, W2F, B2P, XC, N, 64);
  k_gat2<<<(N + 15) / 16, 256, 0, stream>>>(XC, att2, bias2, ln2g, ln2b,
                                            rowptr, ssrc, outW, outb, out, N);
}

// Round 5
// 487.575 us; speedup vs baseline: 1.8196x; 1.0396x over previous
//
#include <hip/hip_runtime.h>

typedef __attribute__((ext_vector_type(8))) short bf16x8;
typedef __attribute__((ext_vector_type(4))) float f32x4;

__device__ __forceinline__ float bf2f(ushort u) {
  union { uint i; float f; } v; v.i = ((uint)u) << 16; return v.f;
}
__device__ __forceinline__ ushort f2bf(float f) {
  union { float f; uint i; } v; v.f = f;
  uint r = (v.i + 0x7FFFu + ((v.i >> 16) & 1u)) >> 16;
  return (ushort)r;
}

// single-instruction butterfly add via DPP (quad_perm / mirrors)
template <int CTRL>
__device__ __forceinline__ float dppadd(float x) {
  union { float f; int i; } a, b;
  a.f = x;
  b.i = __builtin_amdgcn_update_dpp(0, a.i, CTRL, 0xF, 0xF, true);
  return a.f + b.f;
}
#define DPP_X1 0xB1   // quad_perm [1,0,3,2]  (lane^1)
#define DPP_X2 0x4E   // quad_perm [2,3,0,1]  (lane^2)
#define DPP_X7 0x141  // row_half_mirror (lane^7; acts as ^4 after ^1,^2)
#define DPP_XF 0x140  // row_mirror (lane^15; acts as ^8 after ^1,^2,^7)

// ---------------- CSR build ----------------

__global__ __launch_bounds__(256) void k_zero(int* p, int n) {
  int i = blockIdx.x * 256 + threadIdx.x;
  if (i < n) p[i] = 0;
}

__global__ __launch_bounds__(256) void k_hist(const int* __restrict__ ei, int* __restrict__ cnt, int E) {
  int e = blockIdx.x * 256 + threadIdx.x;
  if (e < E) atomicAdd(&cnt[ei[E + e]], 1);
}

__global__ __launch_bounds__(256) void k_scan1(const int* __restrict__ cnt, int* __restrict__ partial, int n) {
  int i = blockIdx.x * 256 + threadIdx.x;
  int v = (i < n) ? cnt[i] : 0;
  #pragma unroll
  for (int m = 1; m < 64; m <<= 1) v += __shfl_xor(v, m);
  __shared__ int sm[4];
  if ((threadIdx.x & 63) == 0) sm[threadIdx.x >> 6] = v;
  __syncthreads();
  if (threadIdx.x == 0) partial[blockIdx.x] = sm[0] + sm[1] + sm[2] + sm[3];
}

__global__ __launch_bounds__(512) void k_scan2(int* partial, int nb) {
  __shared__ int buf[2][512];
  int t = threadIdx.x;
  int v = (t < nb) ? partial[t] : 0;
  buf[0][t] = v;
  __syncthreads();
  int cur = 0;
  for (int off = 1; off < 512; off <<= 1) {
    int x = buf[cur][t];
    if (t >= off) x += buf[cur][t - off];
    buf[cur ^ 1][t] = x;
    __syncthreads();
    cur ^= 1;
  }
  if (t < nb) partial[t] = buf[cur][t] - v;   // exclusive
}

__global__ __launch_bounds__(256) void k_scan3(const int* __restrict__ cnt, const int* __restrict__ partial,
                                               int* __restrict__ rowptr, int* __restrict__ cursor, int n) {
  __shared__ int buf[2][256];
  int t = threadIdx.x;
  int i = blockIdx.x * 256 + t;
  int v = (i < n) ? cnt[i] : 0;
  buf[0][t] = v;
  __syncthreads();
  int cur = 0;
  for (int off = 1; off < 256; off <<= 1) {
    int x = buf[cur][t];
    if (t >= off) x += buf[cur][t - off];
    buf[cur ^ 1][t] = x;
    __syncthreads();
    cur ^= 1;
  }
  if (i < n) {
    int incl = buf[cur][t];
    int base = partial[blockIdx.x];
    int rp = base + incl - v;
    rowptr[i] = rp;
    cursor[i] = rp;
    if (i == n - 1) rowptr[n] = base + incl;
  }
}

// sliced scatter (R4): keeps active ssrc write window L2-resident.
__global__ __launch_bounds__(256) void k_scatter(const int* __restrict__ ei, int* __restrict__ cursor,
                                                 int* __restrict__ ssrc, int E, int NS) {
  int t = threadIdx.x;
  int base = blockIdx.x * 2048;
  int src[8], dst[8];
  #pragma unroll
  for (int j = 0; j < 8; ++j) {
    int idx = base + j * 256 + t;
    bool ok = idx < E;
    src[j] = ok ? ei[idx] : 0;
    dst[j] = ok ? ei[E + idx] : -1;
  }
  for (int s = 0; s < NS; ++s) {
    #pragma unroll
    for (int j = 0; j < 8; ++j) {
      if ((dst[j] >> 13) == s) {
        int pos = atomicAdd(&cursor[dst[j]], 1);
        ssrc[pos] = src[j];
      }
    }
  }
}

// ---------------- x (fp32 row-major) -> bf16 A-fragment order ----------------

__global__ __launch_bounds__(256) void k_conv(const float* __restrict__ x, ushort* __restrict__ AF, int total) {
  int t = blockIdx.x * 256 + threadIdx.x;    // chunk: m = t>>4, k8 = t&15
  if (t >= total) return;
  int m = t >> 4, k8 = t & 15;
  const float* src = x + (size_t)m * 128 + k8 * 8;
  float4 f0 = *(const float4*)src;
  float4 f1 = *(const float4*)(src + 4);
  uint4 o;
  o.x = f2bf(f0.x) | ((uint)f2bf(f0.y) << 16);
  o.y = f2bf(f0.z) | ((uint)f2bf(f0.w) << 16);
  o.z = f2bf(f1.x) | ((uint)f2bf(f1.y) << 16);
  o.w = f2bf(f1.z) | ((uint)f2bf(f1.w) << 16);
  size_t off = ((size_t)(((m >> 4) * 4 + (k8 >> 2)) * 64) + (m & 15) + ((k8 & 3) << 4)) * 8;
  *(uint4*)(AF + off) = o;
}

// ---------------- weight packing into B-fragment order + scaled att ----------------

__global__ __launch_bounds__(256) void k_pack(
    const float* __restrict__ Wl1, const float* __restrict__ bl1,
    const float* __restrict__ Wr1, const float* __restrict__ br1,
    const float* __restrict__ res1W, const float* __restrict__ res1b,
    const float* __restrict__ Wl2, const float* __restrict__ bl2,
    const float* __restrict__ Wr2, const float* __restrict__ br2,
    const float* __restrict__ res2W, const float* __restrict__ res2b,
    const float* __restrict__ skipW, const float* __restrict__ skipb,
    const float* __restrict__ att1, const float* __restrict__ att2,
    ushort* __restrict__ W1F, float* __restrict__ B1P,
    ushort* __restrict__ W2F, float* __restrict__ B2P,
    float* __restrict__ attE, float* __restrict__ at2E) {
  const float LOG2E = 1.4426950408889634f;
  int tid = blockIdx.x * 256 + threadIdx.x;
  if (tid < 49152) {                       // layer-1 weights
    int j = tid & 7, l = (tid >> 3) & 63, ktile = (tid >> 9) & 3, ct = tid >> 11;
    int k = ktile * 32 + ((l >> 4) << 3) + j;
    int n = ct * 16 + (l & 15);
    int sel = n >> 7, jj = n & 127;
    const float* s = sel == 0 ? Wl1 : sel == 1 ? Wr1 : res1W;
    W1F[tid] = f2bf(s[k * 128 + jj]);
  } else if (tid < 57344) {                // layer-2 weights
    int u = tid - 49152;
    int j = u & 7, l = (u >> 3) & 63, ktile = (u >> 9) & 3, ct = u >> 11;
    int k = ktile * 32 + ((l >> 4) << 3) + j;
    int n = ct * 16 + (l & 15);
    int sel = n >> 4, jj = n & 15;
    const float* s = sel == 0 ? Wl2 : sel == 1 ? Wr2 : sel == 2 ? res2W : skipW;
    W2F[u] = f2bf(s[k * 16 + jj]);
  } else if (tid < 57728) {                // layer-1 bias (384)
    int n = tid - 57344;
    int sel = n >> 7, jj = n & 127;
    const float* sb = sel == 0 ? bl1 : sel == 1 ? br1 : res1b;
    B1P[n] = sb[jj];
  } else if (tid < 57792) {                // layer-2 bias (64)
    int n = tid - 57728;
    int sel = n >> 4, jj = n & 15;
    const float* sb = sel == 0 ? bl2 : sel == 1 ? br2 : sel == 2 ? res2b : skipb;
    B2P[n] = sb[jj];
  } else if (tid < 57920) {                // att1 * log2(e)
    int n = tid - 57792;
    attE[n] = att1[n] * LOG2E;
  } else if (tid < 57936) {                // att2 * log2(e)
    int n = tid - 57920;
    at2E[n] = att2[n] * LOG2E;
  }
}

// ---------------- MFMA GEMM with split outputs ----------------
// C cols [arr*csplit, (arr+1)*csplit) -> array O<arr> with row stride csplit.

__global__ __launch_bounds__(256) void k_mfma(
    const ushort* __restrict__ AF, const ushort* __restrict__ WF,
    const float* __restrict__ bias,
    ushort* __restrict__ O0, ushort* __restrict__ O1,
    ushort* __restrict__ O2, ushort* __restrict__ O3,
    int M, int cs_shift) {
  int w = threadIdx.x >> 6, l = threadIdx.x & 63;
  int m0 = blockIdx.x * 64;
  int c0 = blockIdx.y * 64 + w * 16;
  int ct = c0 >> 4;
  f32x4 acc[4] = {};
  #pragma unroll
  for (int kt = 0; kt < 4; ++kt) {
    bf16x8 b = *(const bf16x8*)(WF + ((size_t)((ct * 4 + kt) * 64 + l)) * 8);
    #pragma unroll
    for (int rt = 0; rt < 4; ++rt) {
      bf16x8 a = *(const bf16x8*)(AF + ((size_t)((blockIdx.x * 16 + rt * 4 + kt) * 64 + l)) * 8);
      acc[rt] = __builtin_amdgcn_mfma_f32_16x16x32_bf16(a, b, acc[rt], 0, 0, 0);
    }
  }
  int col = c0 + (l & 15);
  int arr = col >> cs_shift;                   // wave-uniform
  ushort* O = arr == 0 ? O0 : arr == 1 ? O1 : arr == 2 ? O2 : O3;
  int stride = 1 << cs_shift;
  int lcol = col & (stride - 1);
  float bv = bias[col];
  int rbase = m0 + ((l >> 4) << 2);
  #pragma unroll
  for (int rt = 0; rt < 4; ++rt) {
    #pragma unroll
    for (int r = 0; r < 4; ++r) {
      int m = rbase + rt * 16 + r;
      if (m < M) O[(size_t)m * stride + lcol] = f2bf(acc[rt][r] + bv);
    }
  }
}

// ---------------- layer-1 fused ----------------
// one wave per dst node. XLG/XR/RE: separate bf16 arrays, stride 128.
// Edge loop: SGPR indices via readlane, DPP logit reduce, exp2 w/ prescaled att,
// leaky-dot = 0.6(att.m) + 0.4(att.|m|)  (abs = free VOP3 modifier).

#define EDGE1U(u)                                                          \
  {                                                                        \
    float vx = __builtin_bit_cast(float, (u) << 16);                       \
    float vy = __builtin_bit_cast(float, (u) & 0xffff0000u);               \
    float mx = vx + xr.x, my = vy + xr.y;                                  \
    float ta = atv.x * mx + atv.y * my;                                    \
    float tb = atv.x * __builtin_fabsf(mx) + atv.y * __builtin_fabsf(my);  \
    float tt = 0.6f * ta + 0.4f * tb;                                      \
    tt = dppadd<DPP_X1>(tt);                                               \
    tt = dppadd<DPP_X2>(tt);                                               \
    tt = dppadd<DPP_X7>(tt);                                               \
    float p = __builtin_amdgcn_exp2f(tt);                                  \
    accx += p * vx; accy += p * vy; den += p;                              \
  }

__global__ __launch_bounds__(256) void k_gat1(
    const ushort* __restrict__ XLG, const ushort* __restrict__ XR,
    const ushort* __restrict__ RE,
    const float* __restrict__ attE, const float* __restrict__ bias1,
    const float* __restrict__ g1, const float* __restrict__ b1,
    const int* __restrict__ rowptr, const int* __restrict__ ssrc,
    ushort* __restrict__ HF, int n) {
  int lane = threadIdx.x & 63;
  int i = blockIdx.x * 4 + (threadIdx.x >> 6);
  if (i >= n) return;
  int f = lane * 2;
  size_t ib = (size_t)i << 7;
  uint u_self = *(const uint*)(XLG + ib + f);
  float2 xr;
  { uint u = *(const uint*)(XR + ib + f);
    xr = make_float2(__builtin_bit_cast(float, u << 16),
                     __builtin_bit_cast(float, u & 0xffff0000u)); }
  float2 atv = *(const float2*)&attE[f];
  float accx = 0.f, accy = 0.f, den = 0.f;
  EDGE1U(u_self);                              // implicit self-loop
  int e0 = __builtin_amdgcn_readfirstlane(rowptr[i]);
  int e1 = __builtin_amdgcn_readfirstlane(rowptr[i + 1]);
  for (int base = e0; base < e1; base += 64) {
    int cnt = e1 - base; if (cnt > 64) cnt = 64;
    int sidx = ssrc[base + (lane < cnt ? lane : cnt - 1)];   // coalesced
    int j = 0;
    for (; j + 4 <= cnt; j += 4) {
      int s0 = __builtin_amdgcn_readlane(sidx, j);
      int s1 = __builtin_amdgcn_readlane(sidx, j + 1);
      int s2 = __builtin_amdgcn_readlane(sidx, j + 2);
      int s3 = __builtin_amdgcn_readlane(sidx, j + 3);
      uint u0 = *(const uint*)(XLG + ((size_t)(uint)s0 << 7) + f);
      uint u1 = *(const uint*)(XLG + ((size_t)(uint)s1 << 7) + f);
      uint u2 = *(const uint*)(XLG + ((size_t)(uint)s2 << 7) + f);
      uint u3 = *(const uint*)(XLG + ((size_t)(uint)s3 << 7) + f);
      EDGE1U(u0); EDGE1U(u1); EDGE1U(u2); EDGE1U(u3);
    }
    for (; j < cnt; ++j) {
      int s = __builtin_amdgcn_readlane(sidx, j);
      uint u = *(const uint*)(XLG + ((size_t)(uint)s << 7) + f);
      EDGE1U(u);
    }
  }
  float inv = 1.f / (den + 1e-16f);
  float2 bv = *(const float2*)&bias1[f];
  float ox = accx * inv + bv.x, oy = accy * inv + bv.y;
  float s = ox + oy;
  #pragma unroll
  for (int m = 1; m < 64; m <<= 1) s += __shfl_xor(s, m);
  float mu = s * (1.f / 128.f);
  float dx = ox - mu, dy = oy - mu;
  float q = dx * dx + dy * dy;
  #pragma unroll
  for (int m = 1; m < 64; m <<= 1) q += __shfl_xor(q, m);
  float rstd = rsqrtf(q * (1.f / 128.f) + 1e-5f);
  float2 gg = *(const float2*)&g1[f];
  float2 bb = *(const float2*)&b1[f];
  float2 rv;
  { uint u = *(const uint*)(RE + ib + f);
    rv = make_float2(__builtin_bit_cast(float, u << 16),
                     __builtin_bit_cast(float, u & 0xffff0000u)); }
  float yx = dx * rstd * gg.x + bb.x + rv.x;
  float yy = dy * rstd * gg.y + bb.y + rv.y;
  yx = yx > 0.f ? yx : __expf(yx) - 1.f;
  yy = yy > 0.f ? yy : __expf(yy) - 1.f;
  // A-fragment write for GEMM2
  size_t off = (((size_t)(i >> 4) * 4 + (lane >> 4)) * 64 + (i & 15) + ((lane >> 2) & 3) * 16) * 8
               + 2 * (lane & 3);
  *(uint*)(HF + off) = (uint)f2bf(yx) | ((uint)f2bf(yy) << 16);
}

// ---------------- layer-2 fused ----------------
// 16 lanes per node (4 nodes/wave). Split arrays stride 16: XG (gathered xl2),
// XRr (xr2), XE (res2), XS (skip). DPP reduce over 16; fused out-GEMV.

#define EDGE2V(v)                                            \
  {                                                          \
    float m = (v) + xr;                                      \
    float ta = a2 * m;                                       \
    float tb = a2 * __builtin_fabsf(m);                      \
    float tt = 0.6f * ta + 0.4f * tb;                        \
    tt = dppadd<DPP_X1>(tt);                                 \
    tt = dppadd<DPP_X2>(tt);                                 \
    tt = dppadd<DPP_X7>(tt);                                 \
    tt = dppadd<DPP_XF>(tt);                                 \
    float p = __builtin_amdgcn_exp2f(tt);                    \
    acc += p * (v); den += p;                                \
  }

__global__ __launch_bounds__(256) void k_gat2(
    const ushort* __restrict__ XG, const ushort* __restrict__ XRr,
    const ushort* __restrict__ XE, const ushort* __restrict__ XS,
    const float* __restrict__ at2E, const float* __restrict__ bias2,
    const float* __restrict__ g2, const float* __restrict__ b2,
    const int* __restrict__ rowptr, const int* __restrict__ ssrc,
    const float* __restrict__ outW, const float* __restrict__ outB,
    float* __restrict__ Out, int n) {
  __shared__ float sW[1024];
  __shared__ float sB[64];
  int t = threadIdx.x;
  for (int idx = t; idx < 1024; idx += 256) sW[idx] = outW[idx];
  if (t < 64) sB[t] = outB[t];
  __syncthreads();
  int c = t & 15;
  int i = blockIdx.x * 16 + (t >> 4);
  if (i >= n) return;
  size_t ib = (size_t)i << 4;
  float xl = bf2f(XG[ib + c]), xr = bf2f(XRr[ib + c]);
  float resv = bf2f(XE[ib + c]), skipv = bf2f(XS[ib + c]);
  float a2 = at2E[c];
  float acc = 0.f, den = 0.f;
  EDGE2V(xl);                                  // self-loop
  int e0 = rowptr[i], e1 = rowptr[i + 1];
  int e = e0;
  for (; e + 4 <= e1; e += 4) {
    int s0 = ssrc[e], s1 = ssrc[e + 1], s2 = ssrc[e + 2], s3 = ssrc[e + 3];
    float v0 = bf2f(XG[((size_t)(uint)s0 << 4) + c]);
    float v1 = bf2f(XG[((size_t)(uint)s1 << 4) + c]);
    float v2 = bf2f(XG[((size_t)(uint)s2 << 4) + c]);
    float v3 = bf2f(XG[((size_t)(uint)s3 << 4) + c]);
    EDGE2V(v0); EDGE2V(v1); EDGE2V(v2); EDGE2V(v3);
  }
  for (; e < e1; ++e) {
    int s = ssrc[e];
    float v = bf2f(XG[((size_t)(uint)s << 4) + c]);
    EDGE2V(v);
  }
  float o = acc / (den + 1e-16f) + bias2[c];
  float s = o;
  s = dppadd<DPP_X1>(s); s = dppadd<DPP_X2>(s); s = dppadd<DPP_X7>(s); s = dppadd<DPP_XF>(s);
  float mu = s * (1.f / 16.f);
  float d = o - mu;
  float q = d * d;
  q = dppadd<DPP_X1>(q); q = dppadd<DPP_X2>(q); q = dppadd<DPP_X7>(q); q = dppadd<DPP_XF>(q);
  float rstd = rsqrtf(q * (1.f / 16.f) + 1e-5f);
  float y = d * rstd * g2[c] + b2[c] + resv;
  y = y > 0.f ? y : __expf(y) - 1.f;
  y += skipv;
  float a0 = sB[c * 4 + 0], a1 = sB[c * 4 + 1], ao2 = sB[c * 4 + 2], a3 = sB[c * 4 + 3];
  #pragma unroll
  for (int cc = 0; cc < 16; ++cc) {
    float h = __shfl(y, cc, 16);
    a0 += h * sW[cc * 64 + c * 4 + 0];
    a1 += h * sW[cc * 64 + c * 4 + 1];
    ao2 += h * sW[cc * 64 + c * 4 + 2];
    a3 += h * sW[cc * 64 + c * 4 + 3];
  }
  *(float4*)&Out[(size_t)i * 64 + c * 4] = make_float4(a0, a1, ao2, a3);
}

// ---------------- launch ----------------

extern "C" void kernel_launch(void* const* d_in, const int* in_sizes, int n_in,
                              void* d_out, int out_size, void* d_ws, size_t ws_size,
                              hipStream_t stream) {
  const float* x     = (const float*)d_in[0];
  const int*   ei    = (const int*)d_in[1];
  const float* Wl1   = (const float*)d_in[2];
  const float* bl1   = (const float*)d_in[3];
  const float* Wr1   = (const float*)d_in[4];
  const float* br1   = (const float*)d_in[5];
  const float* att1  = (const float*)d_in[6];
  const float* bias1 = (const float*)d_in[7];
  const float* Wl2   = (const float*)d_in[8];
  const float* bl2   = (const float*)d_in[9];
  const float* Wr2   = (const float*)d_in[10];
  const float* br2   = (const float*)d_in[11];
  const float* att2  = (const float*)d_in[12];
  const float* bias2 = (const float*)d_in[13];
  const float* ln1g  = (const float*)d_in[14];
  const float* ln1b  = (const float*)d_in[15];
  const float* ln2g  = (const float*)d_in[16];
  const float* ln2b  = (const float*)d_in[17];
  const float* res1W = (const float*)d_in[18];
  const float* res1b = (const float*)d_in[19];
  const float* res2W = (const float*)d_in[20];
  const float* res2b = (const float*)d_in[21];
  const float* skipW = (const float*)d_in[22];
  const float* skipb = (const float*)d_in[23];
  const float* outW  = (const float*)d_in[24];
  const float* outb  = (const float*)d_in[25];
  int N = in_sizes[0] / 128;
  int E = in_sizes[1] / 2;
  float* out = (float*)d_out;

  int nblk = (N + 63) / 64;            // 64-row GEMM blocks
  int ngrp = nblk * 4;                 // padded 16-row fragment groups

  // workspace layout (16B aligned)
  ushort* XF   = (ushort*)d_ws;                      // ngrp*2048
  ushort* XLG  = XF + (size_t)ngrp * 2048;           // N*128 (gathered xl)
  ushort* XR1  = XLG + (size_t)N * 128;              // N*128
  ushort* RE1  = XR1 + (size_t)N * 128;              // N*128
  ushort* HF   = RE1 + (size_t)N * 128;              // ngrp*2048
  ushort* XG2  = HF + (size_t)ngrp * 2048;           // N*16 (gathered xl2)
  ushort* X2R  = XG2 + (size_t)N * 16;               // N*16
  ushort* X2E  = X2R + (size_t)N * 16;               // N*16
  ushort* X2S  = X2E + (size_t)N * 16;               // N*16
  ushort* W1F  = X2S + (size_t)N * 16;               // 49152
  ushort* W2F  = W1F + 49152;                        // 8192
  float*  B1P  = (float*)(W2F + 8192);               // 384
  float*  B2P  = B1P + 384;                          // 64
  float*  attE = B2P + 64;                           // 128
  float*  at2E = attE + 128;                         // 16
  int* cnt     = (int*)(at2E + 16);
  int* cursor  = cnt + N;
  int* rowptr  = cursor + N;
  int* ssrc    = rowptr + N + 1;
  int* partial = ssrc + E;

  int nbS = (N + 255) / 256;
  int nbE = (E + 255) / 256;
  int NS = ((N - 1) >> 13) + 1;        // dst slices of 8192 nodes

  // weight packing + x conversion (independent of CSR)
  k_pack<<<227, 256, 0, stream>>>(Wl1, bl1, Wr1, br1, res1W, res1b,
                                  Wl2, bl2, Wr2, br2, res2W, res2b, skipW, skipb,
                                  att1, att2, W1F, B1P, W2F, B2P, attE, at2E);
  k_conv<<<(N * 16 + 255) / 256, 256, 0, stream>>>(x, XF, N * 16);

  // CSR build (self-loops handled in-kernel, not stored)
  k_zero<<<nbS, 256, 0, stream>>>(cnt, N);
  k_hist<<<nbE, 256, 0, stream>>>(ei, cnt, E);
  k_scan1<<<nbS, 256, 0, stream>>>(cnt, partial, N);
  k_scan2<<<1, 512, 0, stream>>>(partial, nbS);
  k_scan3<<<nbS, 256, 0, stream>>>(cnt, partial, rowptr, cursor, N);
  k_scatter<<<(E + 2047) / 2048, 256, 0, stream>>>(ei, cursor, ssrc, E, NS);

  // layer-1 node GEMM -> split arrays XLG|XR1|RE1 (stride 128)
  dim3 g1g(nblk, 6);
  k_mfma<<<g1g, 256, 0, stream>>>(XF, W1F, B1P, XLG, XR1, RE1, XLG, N, 7);

  // layer-1 edge+node fused (writes GEMM2 A-fragments)
  k_gat1<<<(N + 3) / 4, 256, 0, stream>>>(XLG, XR1, RE1, attE, bias1, ln1g, ln1b,
                                          rowptr, ssrc, HF, N);

  // layer-2 GEMM -> split arrays XG2|X2R|X2E|X2S (stride 16)
  dim3 g2g(nblk, 1);
  k_mfma<<<g2g, 256, 0, stream>>>(HF, W2F, B2P, XG2, X2R, X2E, X2S, N, 4);
  k_gat2<<<(N + 15) / 16, 256, 0, stream>>>(XG2, X2R, X2E, X2S, at2E, bias2, ln2g, ln2b,
                                            rowptr, ssrc, outW, outb, out, N);
}

// Round 6
// 459.038 us; speedup vs baseline: 1.9327x; 1.0622x over previous
//
#include <hip/hip_runtime.h>

typedef __attribute__((ext_vector_type(8))) short bf16x8;
typedef __attribute__((ext_vector_type(4))) float f32x4;

__device__ __forceinline__ float bf2f(ushort u) {
  union { uint i; float f; } v; v.i = ((uint)u) << 16; return v.f;
}
__device__ __forceinline__ ushort f2bf(float f) {
  union { float f; uint i; } v; v.f = f;
  uint r = (v.i + 0x7FFFu + ((v.i >> 16) & 1u)) >> 16;
  return (ushort)r;
}
__device__ __forceinline__ float blo(uint u) { return __builtin_bit_cast(float, u << 16); }
__device__ __forceinline__ float bhi(uint u) { return __builtin_bit_cast(float, u & 0xffff0000u); }

template <int CTRL>
__device__ __forceinline__ float dppadd(float x) {
  union { float f; int i; } a, b;
  a.f = x;
  b.i = __builtin_amdgcn_update_dpp(0, a.i, CTRL, 0xF, 0xF, true);
  return a.f + b.f;
}
#define DPP_X1 0xB1   // quad_perm [1,0,3,2]
#define DPP_X2 0x4E   // quad_perm [2,3,0,1]
#define DPP_X7 0x141  // row_half_mirror
#define DPP_XF 0x140  // row_mirror

// ---------------- K1: pack + conv + zero (independent init work) ----------------

__global__ __launch_bounds__(256) void k_init(
    const float* __restrict__ x, ushort* __restrict__ XF,
    const float* __restrict__ Wl1, const float* __restrict__ bl1,
    const float* __restrict__ Wr1, const float* __restrict__ br1,
    const float* __restrict__ res1W, const float* __restrict__ res1b,
    const float* __restrict__ Wl2, const float* __restrict__ bl2,
    const float* __restrict__ Wr2, const float* __restrict__ br2,
    const float* __restrict__ res2W, const float* __restrict__ res2b,
    const float* __restrict__ skipW, const float* __restrict__ skipb,
    const float* __restrict__ att1, const float* __restrict__ att2,
    ushort* __restrict__ W1F, float* __restrict__ B1P,
    ushort* __restrict__ W2F, float* __restrict__ B2P,
    float* __restrict__ at6, float* __restrict__ at4, float* __restrict__ at2E,
    int* __restrict__ cnt, int N) {
  const float LOG2E = 1.4426950408889634f;
  int b = blockIdx.x, t = threadIdx.x;
  int CB = (N * 16 + 255) >> 8;
  if (b < 227) {                                 // ---- pack ----
    int tid = b * 256 + t;
    if (tid < 49152) {
      int j = tid & 7, l = (tid >> 3) & 63, ktile = (tid >> 9) & 3, ct = tid >> 11;
      int k = ktile * 32 + ((l >> 4) << 3) + j;
      int n = ct * 16 + (l & 15);
      int sel = n >> 7, jj = n & 127;
      const float* s = sel == 0 ? Wl1 : sel == 1 ? Wr1 : res1W;
      W1F[tid] = f2bf(s[k * 128 + jj]);
    } else if (tid < 57344) {
      int u = tid - 49152;
      int j = u & 7, l = (u >> 3) & 63, ktile = (u >> 9) & 3, ct = u >> 11;
      int k = ktile * 32 + ((l >> 4) << 3) + j;
      int n = ct * 16 + (l & 15);
      int sel = n >> 4, jj = n & 15;
      const float* s = sel == 0 ? Wl2 : sel == 1 ? Wr2 : sel == 2 ? res2W : skipW;
      W2F[u] = f2bf(s[k * 16 + jj]);
    } else if (tid < 57728) {
      int n = tid - 57344;
      int sel = n >> 7, jj = n & 127;
      const float* sb = sel == 0 ? bl1 : sel == 1 ? br1 : res1b;
      B1P[n] = sb[jj];
    } else if (tid < 57792) {
      int n = tid - 57728;
      int sel = n >> 4, jj = n & 15;
      const float* sb = sel == 0 ? bl2 : sel == 1 ? br2 : sel == 2 ? res2b : skipb;
      B2P[n] = sb[jj];
    } else if (tid < 57920) {
      int n = tid - 57792;
      at6[n] = att1[n] * 0.6f * LOG2E;
    } else if (tid < 58048) {
      int n = tid - 57920;
      at4[n] = att1[n] * 0.4f * LOG2E;
    } else if (tid < 58064) {
      int n = tid - 58048;
      at2E[n] = att2[n] * LOG2E;
    }
  } else if (b < 227 + CB) {                     // ---- conv: x -> A-fragments ----
    int t2 = (b - 227) * 256 + t;
    if (t2 < N * 16) {
      int m = t2 >> 4, k8 = t2 & 15;
      const float* src = x + (size_t)m * 128 + k8 * 8;
      float4 f0 = *(const float4*)src;
      float4 f1 = *(const float4*)(src + 4);
      uint4 o;
      o.x = f2bf(f0.x) | ((uint)f2bf(f0.y) << 16);
      o.y = f2bf(f0.z) | ((uint)f2bf(f0.w) << 16);
      o.z = f2bf(f1.x) | ((uint)f2bf(f1.y) << 16);
      o.w = f2bf(f1.z) | ((uint)f2bf(f1.w) << 16);
      size_t off = ((size_t)(((m >> 4) * 4 + (k8 >> 2)) * 64) + (m & 15) + ((k8 & 3) << 4)) * 8;
      *(uint4*)(XF + off) = o;
    }
  } else {                                       // ---- zero cnt ----
    int idx = (b - 227 - CB) * 256 + t;
    if (idx < N) cnt[idx] = 0;
  }
}

// ---------------- K2: histogram (4 edges/thread) ----------------

__global__ __launch_bounds__(256) void k_hist(const int* __restrict__ ei, int* __restrict__ cnt, int E) {
  int e4 = (blockIdx.x * 256 + threadIdx.x) * 4;
  if (e4 + 3 < E) {
    int4 d = *(const int4*)&ei[E + e4];
    atomicAdd(&cnt[d.x], 1); atomicAdd(&cnt[d.y], 1);
    atomicAdd(&cnt[d.z], 1); atomicAdd(&cnt[d.w], 1);
  } else {
    for (int e = e4; e < E; ++e) atomicAdd(&cnt[ei[E + e]], 1);
  }
}

// ---------------- K3: per-block sums ----------------

__global__ __launch_bounds__(256) void k_scan1(const int* __restrict__ cnt, int* __restrict__ partial, int n) {
  int i = blockIdx.x * 256 + threadIdx.x;
  int v = (i < n) ? cnt[i] : 0;
  #pragma unroll
  for (int m = 1; m < 64; m <<= 1) v += __shfl_xor(v, m);
  __shared__ int sm[4];
  if ((threadIdx.x & 63) == 0) sm[threadIdx.x >> 6] = v;
  __syncthreads();
  if (threadIdx.x == 0) partial[blockIdx.x] = sm[0] + sm[1] + sm[2] + sm[3];
}

// ---------------- K4: scan with inline lookback (replaces scan2+scan3) ----------------

__global__ __launch_bounds__(256) void k_scan3lb(const int* __restrict__ cnt, const int* __restrict__ partial,
                                                 int* __restrict__ rowptr, int* __restrict__ cursor, int n) {
  int t = threadIdx.x;
  int b = blockIdx.x;
  // base = sum of partial[0..b)
  int acc = 0;
  for (int j = t; j < b; j += 256) acc += partial[j];
  #pragma unroll
  for (int m = 1; m < 64; m <<= 1) acc += __shfl_xor(acc, m);
  __shared__ int sm[4];
  if ((t & 63) == 0) sm[t >> 6] = acc;
  __syncthreads();
  int base = sm[0] + sm[1] + sm[2] + sm[3];
  // Hillis-Steele inclusive scan of this block's 256 counts
  __shared__ int buf[2][256];
  int i = b * 256 + t;
  int v = (i < n) ? cnt[i] : 0;
  buf[0][t] = v;
  __syncthreads();
  int cur = 0;
  for (int off = 1; off < 256; off <<= 1) {
    int x = buf[cur][t];
    if (t >= off) x += buf[cur][t - off];
    buf[cur ^ 1][t] = x;
    __syncthreads();
    cur ^= 1;
  }
  if (i < n) {
    int incl = buf[cur][t];
    int rp = base + incl - v;
    rowptr[i] = rp;
    cursor[i] = rp;
    if (i == n - 1) rowptr[n] = base + incl;
  }
}

// ---------------- K5: sliced scatter + GEMM1 (independent, one dispatch) ----------------
// blocks [0,nScat): scatter; rest: bf16 MFMA GEMM1 -> split arrays stride 128.

__global__ __launch_bounds__(256) void k_scatgemm(
    const int* __restrict__ ei, int* __restrict__ cursor, int* __restrict__ ssrc, int E, int NS, int nScat,
    const ushort* __restrict__ AF, const ushort* __restrict__ WF, const float* __restrict__ bias,
    ushort* __restrict__ O0, ushort* __restrict__ O1, ushort* __restrict__ O2,
    int M, int nblk) {
  int b = blockIdx.x;
  int t = threadIdx.x;
  if (b < nScat) {
    int base = b * 2048;
    int src[8], dst[8];
    #pragma unroll
    for (int j = 0; j < 8; ++j) {
      int idx = base + j * 256 + t;
      bool ok = idx < E;
      src[j] = ok ? ei[idx] : 0;
      dst[j] = ok ? ei[E + idx] : -1;
    }
    for (int s = 0; s < NS; ++s) {
      #pragma unroll
      for (int j = 0; j < 8; ++j) {
        if ((dst[j] >> 13) == s) {
          int pos = atomicAdd(&cursor[dst[j]], 1);
          ssrc[pos] = src[j];
        }
      }
    }
  } else {
    int bb = b - nScat;
    int by = bb / nblk;
    int bx = bb - by * nblk;
    int w = t >> 6, l = t & 63;
    int m0 = bx * 64;
    int c0 = by * 64 + w * 16;
    int ct = c0 >> 4;
    f32x4 acc[4] = {};
    #pragma unroll
    for (int kt = 0; kt < 4; ++kt) {
      bf16x8 bfr = *(const bf16x8*)(WF + ((size_t)((ct * 4 + kt) * 64 + l)) * 8);
      #pragma unroll
      for (int rt = 0; rt < 4; ++rt) {
        bf16x8 a = *(const bf16x8*)(AF + ((size_t)((bx * 16 + rt * 4 + kt) * 64 + l)) * 8);
        acc[rt] = __builtin_amdgcn_mfma_f32_16x16x32_bf16(a, bfr, acc[rt], 0, 0, 0);
      }
    }
    int col = c0 + (l & 15);
    int arr = col >> 7;                          // wave-uniform (384 cols -> 3 arrays)
    ushort* O = arr == 0 ? O0 : arr == 1 ? O1 : O2;
    int lcol = col & 127;
    float bv = bias[col];
    int rbase = m0 + ((l >> 4) << 2);
    #pragma unroll
    for (int rt = 0; rt < 4; ++rt) {
      #pragma unroll
      for (int r = 0; r < 4; ++r) {
        int m = rbase + rt * 16 + r;
        if (m < M) O[(size_t)m * 128 + lcol] = f2bf(acc[rt][r] + bv);
      }
    }
  }
}

// ---------------- MFMA GEMM2 (stride-16 split outputs) ----------------

__global__ __launch_bounds__(256) void k_mfma2(
    const ushort* __restrict__ AF, const ushort* __restrict__ WF,
    const float* __restrict__ bias,
    ushort* __restrict__ O0, ushort* __restrict__ O1,
    ushort* __restrict__ O2, ushort* __restrict__ O3, int M) {
  int w = threadIdx.x >> 6, l = threadIdx.x & 63;
  int m0 = blockIdx.x * 64;
  int c0 = w * 16;
  int ct = c0 >> 4;
  f32x4 acc[4] = {};
  #pragma unroll
  for (int kt = 0; kt < 4; ++kt) {
    bf16x8 b = *(const bf16x8*)(WF + ((size_t)((ct * 4 + kt) * 64 + l)) * 8);
    #pragma unroll
    for (int rt = 0; rt < 4; ++rt) {
      bf16x8 a = *(const bf16x8*)(AF + ((size_t)((blockIdx.x * 16 + rt * 4 + kt) * 64 + l)) * 8);
      acc[rt] = __builtin_amdgcn_mfma_f32_16x16x32_bf16(a, b, acc[rt], 0, 0, 0);
    }
  }
  int col = c0 + (l & 15);
  int arr = col >> 4;
  ushort* O = arr == 0 ? O0 : arr == 1 ? O1 : arr == 2 ? O2 : O3;
  int lcol = col & 15;
  float bv = bias[col];
  int rbase = m0 + ((l >> 4) << 2);
  #pragma unroll
  for (int rt = 0; rt < 4; ++rt) {
    #pragma unroll
    for (int r = 0; r < 4; ++r) {
      int m = rbase + rt * 16 + r;
      if (m < M) O[(size_t)m * 16 + lcol] = f2bf(acc[rt][r] + bv);
    }
  }
}

// ---------------- K6: layer-1 fused, 2 edges per wave ----------------
// one wave per dst node; 32 lanes per edge, 4 feats/lane.
// halves (lanes 0-31 / 32-63) process different edges, combined at the end.

#define EDGE1B(u, MASKHI)                                              \
  {                                                                    \
    float v0 = blo((u).x), v1 = bhi((u).x);                            \
    float v2 = blo((u).y), v3 = bhi((u).y);                            \
    float m0 = v0 + xr0, m1 = v1 + xr1, m2 = v2 + xr2, m3 = v3 + xr3;  \
    float d = a6.x * m0 + a4.x * __builtin_fabsf(m0);                  \
    d += a6.y * m1; d += a4.y * __builtin_fabsf(m1);                   \
    d += a6.z * m2; d += a4.z * __builtin_fabsf(m2);                   \
    d += a6.w * m3; d += a4.w * __builtin_fabsf(m3);                   \
    d = dppadd<DPP_X1>(d);                                             \
    d = dppadd<DPP_X2>(d);                                             \
    float p = __builtin_amdgcn_exp2f(d);                               \
    if (MASKHI) p = hi ? 0.f : p;                                      \
    acc0 += p * v0; acc1 += p * v1; acc2 += p * v2; acc3 += p * v3;    \
    den += p;                                                          \
  }

__global__ __launch_bounds__(256) void k_gat1(
    const ushort* __restrict__ XLG, const ushort* __restrict__ XR,
    const ushort* __restrict__ RE,
    const float* __restrict__ at6, const float* __restrict__ at4,
    const float* __restrict__ bias1,
    const float* __restrict__ g1, const float* __restrict__ b1,
    const int* __restrict__ rowptr, const int* __restrict__ ssrc,
    ushort* __restrict__ HF, int n) {
  int lane = threadIdx.x & 63;
  int i = blockIdx.x * 4 + (threadIdx.x >> 6);
  if (i >= n) return;
  int l32 = lane & 31;
  bool hi = lane >= 32;
  int fb = l32 * 4;                        // this lane's first feature
  size_t rowb = (size_t)i << 8;            // 256 B per row
  uint2 uxr = *(const uint2*)((const char*)XR + rowb + (fb << 1));
  float xr0 = blo(uxr.x), xr1 = bhi(uxr.x), xr2 = blo(uxr.y), xr3 = bhi(uxr.y);
  float4 a6 = *(const float4*)&at6[fb];
  float4 a4 = *(const float4*)&at4[fb];
  float acc0 = 0.f, acc1 = 0.f, acc2 = 0.f, acc3 = 0.f, den = 0.f;
  // self loop (half 0 only accumulates)
  {
    uint2 us = *(const uint2*)((const char*)XLG + rowb + (fb << 1));
    EDGE1B(us, true);
  }
  int e0 = __builtin_amdgcn_readfirstlane(rowptr[i]);
  int e1 = __builtin_amdgcn_readfirstlane(rowptr[i + 1]);
  for (int base = e0; base < e1; base += 64) {
    int cnt = e1 - base; if (cnt > 64) cnt = 64;
    int sidx = ssrc[base + (lane < cnt ? lane : cnt - 1)];
    int j = 0;
    for (; j + 4 <= cnt; j += 4) {         // 2 pairs = 4 edges, 2 loads in flight
      int s0 = __builtin_amdgcn_readlane(sidx, j);
      int s1 = __builtin_amdgcn_readlane(sidx, j + 1);
      int s2 = __builtin_amdgcn_readlane(sidx, j + 2);
      int s3 = __builtin_amdgcn_readlane(sidx, j + 3);
      int rA = hi ? s1 : s0;
      int rB = hi ? s3 : s2;
      uint2 uA = *(const uint2*)((const char*)XLG + ((size_t)(uint)rA << 8) + (fb << 1));
      uint2 uB = *(const uint2*)((const char*)XLG + ((size_t)(uint)rB << 8) + (fb << 1));
      EDGE1B(uA, false);
      EDGE1B(uB, false);
    }
    for (; j + 2 <= cnt; j += 2) {
      int s0 = __builtin_amdgcn_readlane(sidx, j);
      int s1 = __builtin_amdgcn_readlane(sidx, j + 1);
      int r = hi ? s1 : s0;
      uint2 u = *(const uint2*)((const char*)XLG + ((size_t)(uint)r << 8) + (fb << 1));
      EDGE1B(u, false);
    }
    if (j < cnt) {                         // odd tail: half 0 only
      int s0 = __builtin_amdgcn_readlane(sidx, j);
      uint2 u = *(const uint2*)((const char*)XLG + ((size_t)(uint)s0 << 8) + (fb << 1));
      EDGE1B(u, true);
    }
  }
  // combine halves
  acc0 += __shfl_xor(acc0, 32);
  acc1 += __shfl_xor(acc1, 32);
  acc2 += __shfl_xor(acc2, 32);
  acc3 += __shfl_xor(acc3, 32);
  den  += __shfl_xor(den, 32);
  float inv = 1.f / (den + 1e-16f);
  float4 bv = *(const float4*)&bias1[fb];
  float o0 = acc0 * inv + bv.x, o1 = acc1 * inv + bv.y;
  float o2 = acc2 * inv + bv.z, o3 = acc3 * inv + bv.w;
  // LayerNorm over 128 feats (distributed 4/lane over 32 lanes; halves identical)
  float s = o0 + o1 + o2 + o3;
  #pragma unroll
  for (int m = 1; m < 32; m <<= 1) s += __shfl_xor(s, m);
  float mu = s * (1.f / 128.f);
  float d0 = o0 - mu, d1 = o1 - mu, d2 = o2 - mu, d3 = o3 - mu;
  float q = d0 * d0 + d1 * d1 + d2 * d2 + d3 * d3;
  #pragma unroll
  for (int m = 1; m < 32; m <<= 1) q += __shfl_xor(q, m);
  float rstd = rsqrtf(q * (1.f / 128.f) + 1e-5f);
  float4 gg = *(const float4*)&g1[fb];
  float4 bb = *(const float4*)&b1[fb];
  uint2 ur = *(const uint2*)((const char*)RE + rowb + (fb << 1));
  float r0 = blo(ur.x), r1 = bhi(ur.x), r2 = blo(ur.y), r3 = bhi(ur.y);
  float y0 = d0 * rstd * gg.x + bb.x + r0;
  float y1 = d1 * rstd * gg.y + bb.y + r1;
  float y2 = d2 * rstd * gg.z + bb.z + r2;
  float y3 = d3 * rstd * gg.w + bb.w + r3;
  y0 = y0 > 0.f ? y0 : __expf(y0) - 1.f;
  y1 = y1 > 0.f ? y1 : __expf(y1) - 1.f;
  y2 = y2 > 0.f ? y2 : __expf(y2) - 1.f;
  y3 = y3 > 0.f ? y3 : __expf(y3) - 1.f;
  if (!hi) {                               // half 0 writes A-fragments for GEMM2
    int k8 = l32 >> 1;
    size_t slot = ((size_t)(i >> 4) * 4 + (k8 >> 2)) * 64 + (i & 15) + ((k8 & 3) << 4);
    uint2 o;
    o.x = (uint)f2bf(y0) | ((uint)f2bf(y1) << 16);
    o.y = (uint)f2bf(y2) | ((uint)f2bf(y3) << 16);
    *(uint2*)(HF + slot * 8 + (l32 & 1) * 4) = o;
  }
}

// ---------------- K8: layer-2 fused ----------------

#define EDGE2V(v)                                            \
  {                                                          \
    float m = (v) + xr;                                      \
    float ta = a2 * m;                                       \
    float tb = a2 * __builtin_fabsf(m);                      \
    float tt = 0.6f * ta + 0.4f * tb;                        \
    tt = dppadd<DPP_X1>(tt);                                 \
    tt = dppadd<DPP_X2>(tt);                                 \
    tt = dppadd<DPP_X7>(tt);                                 \
    tt = dppadd<DPP_XF>(tt);                                 \
    float p = __builtin_amdgcn_exp2f(tt);                    \
    acc += p * (v); den += p;                                \
  }

__global__ __launch_bounds__(256) void k_gat2(
    const ushort* __restrict__ XG, const ushort* __restrict__ XRr,
    const ushort* __restrict__ XE, const ushort* __restrict__ XS,
    const float* __restrict__ at2E, const float* __restrict__ bias2,
    const float* __restrict__ g2, const float* __restrict__ b2,
    const int* __restrict__ rowptr, const int* __restrict__ ssrc,
    const float* __restrict__ outW, const float* __restrict__ outB,
    float* __restrict__ Out, int n) {
  __shared__ float sW[1024];
  __shared__ float sB[64];
  int t = threadIdx.x;
  for (int idx = t; idx < 1024; idx += 256) sW[idx] = outW[idx];
  if (t < 64) sB[t] = outB[t];
  __syncthreads();
  int c = t & 15;
  int i = blockIdx.x * 16 + (t >> 4);
  if (i >= n) return;
  size_t ib = (size_t)i << 4;
  float xl = bf2f(XG[ib + c]), xr = bf2f(XRr[ib + c]);
  float resv = bf2f(XE[ib + c]), skipv = bf2f(XS[ib + c]);
  float a2 = at2E[c];
  float acc = 0.f, den = 0.f;
  EDGE2V(xl);
  int e0 = rowptr[i], e1 = rowptr[i + 1];
  int e = e0;
  for (; e + 4 <= e1; e += 4) {
    int s0 = ssrc[e], s1 = ssrc[e + 1], s2 = ssrc[e + 2], s3 = ssrc[e + 3];
    float v0 = bf2f(XG[((size_t)(uint)s0 << 4) + c]);
    float v1 = bf2f(XG[((size_t)(uint)s1 << 4) + c]);
    float v2 = bf2f(XG[((size_t)(uint)s2 << 4) + c]);
    float v3 = bf2f(XG[((size_t)(uint)s3 << 4) + c]);
    EDGE2V(v0); EDGE2V(v1); EDGE2V(v2); EDGE2V(v3);
  }
  for (; e < e1; ++e) {
    int s = ssrc[e];
    float v = bf2f(XG[((size_t)(uint)s << 4) + c]);
    EDGE2V(v);
  }
  float o = acc / (den + 1e-16f) + bias2[c];
  float s = o;
  s = dppadd<DPP_X1>(s); s = dppadd<DPP_X2>(s); s = dppadd<DPP_X7>(s); s = dppadd<DPP_XF>(s);
  float mu = s * (1.f / 16.f);
  float d = o - mu;
  float q = d * d;
  q = dppadd<DPP_X1>(q); q = dppadd<DPP_X2>(q); q = dppadd<DPP_X7>(q); q = dppadd<DPP_XF>(q);
  float rstd = rsqrtf(q * (1.f / 16.f) + 1e-5f);
  float y = d * rstd * g2[c] + b2[c] + resv;
  y = y > 0.f ? y : __expf(y) - 1.f;
  y += skipv;
  float a0 = sB[c * 4 + 0], a1 = sB[c * 4 + 1], ao2 = sB[c * 4 + 2], a3 = sB[c * 4 + 3];
  #pragma unroll
  for (int cc = 0; cc < 16; ++cc) {
    float h = __shfl(y, cc, 16);
    a0 += h * sW[cc * 64 + c * 4 + 0];
    a1 += h * sW[cc * 64 + c * 4 + 1];
    ao2 += h * sW[cc * 64 + c * 4 + 2];
    a3 += h * sW[cc * 64 + c * 4 + 3];
  }
  *(float4*)&Out[(size_t)i * 64 + c * 4] = make_float4(a0, a1, ao2, a3);
}

// ---------------- launch ----------------

extern "C" void kernel_launch(void* const* d_in, const int* in_sizes, int n_in,
                              void* d_out, int out_size, void* d_ws, size_t ws_size,
                              hipStream_t stream) {
  const float* x     = (const float*)d_in[0];
  const int*   ei    = (const int*)d_in[1];
  const float* Wl1   = (const float*)d_in[2];
  const float* bl1   = (const float*)d_in[3];
  const float* Wr1   = (const float*)d_in[4];
  const float* br1   = (const float*)d_in[5];
  const float* att1  = (const float*)d_in[6];
  const float* bias1 = (const float*)d_in[7];
  const float* Wl2   = (const float*)d_in[8];
  const float* bl2   = (const float*)d_in[9];
  const float* Wr2   = (const float*)d_in[10];
  const float* br2   = (const float*)d_in[11];
  const float* att2  = (const float*)d_in[12];
  const float* bias2 = (const float*)d_in[13];
  const float* ln1g  = (const float*)d_in[14];
  const float* ln1b  = (const float*)d_in[15];
  const float* ln2g  = (const float*)d_in[16];
  const float* ln2b  = (const float*)d_in[17];
  const float* res1W = (const float*)d_in[18];
  const float* res1b = (const float*)d_in[19];
  const float* res2W = (const float*)d_in[20];
  const float* res2b = (const float*)d_in[21];
  const float* skipW = (const float*)d_in[22];
  const float* skipb = (const float*)d_in[23];
  const float* outW  = (const float*)d_in[24];
  const float* outb  = (const float*)d_in[25];
  int N = in_sizes[0] / 128;
  int E = in_sizes[1] / 2;
  float* out = (float*)d_out;

  int nblk = (N + 63) / 64;
  int ngrp = nblk * 4;

  // workspace layout (16B aligned)
  ushort* XF   = (ushort*)d_ws;                      // ngrp*2048
  ushort* XLG  = XF + (size_t)ngrp * 2048;           // N*128
  ushort* XR1  = XLG + (size_t)N * 128;              // N*128
  ushort* RE1  = XR1 + (size_t)N * 128;              // N*128
  ushort* HF   = RE1 + (size_t)N * 128;              // ngrp*2048
  ushort* XG2  = HF + (size_t)ngrp * 2048;           // N*16
  ushort* X2R  = XG2 + (size_t)N * 16;
  ushort* X2E  = X2R + (size_t)N * 16;
  ushort* X2S  = X2E + (size_t)N * 16;
  ushort* W1F  = X2S + (size_t)N * 16;               // 49152
  ushort* W2F  = W1F + 49152;                        // 8192
  float*  B1P  = (float*)(W2F + 8192);               // 384
  float*  B2P  = B1P + 384;                          // 64
  float*  at6  = B2P + 64;                           // 128
  float*  at4  = at6 + 128;                          // 128
  float*  at2E = at4 + 128;                          // 16
  int* cnt     = (int*)(at2E + 16);
  int* cursor  = cnt + N;
  int* rowptr  = cursor + N;
  int* ssrc    = rowptr + N + 1;
  int* partial = ssrc + E;

  int nbS = (N + 255) / 256;
  int CB  = (N * 16 + 255) / 256;
  int NS  = ((N - 1) >> 13) + 1;
  int nScat = (E + 2047) / 2048;

  // K1: pack + conv + zero
  k_init<<<227 + CB + nbS, 256, 0, stream>>>(x, XF, Wl1, bl1, Wr1, br1, res1W, res1b,
                                             Wl2, bl2, Wr2, br2, res2W, res2b, skipW, skipb,
                                             att1, att2, W1F, B1P, W2F, B2P, at6, at4, at2E,
                                             cnt, N);
  // K2: histogram
  k_hist<<<(E + 1023) / 1024, 256, 0, stream>>>(ei, cnt, E);
  // K3/K4: scan
  k_scan1<<<nbS, 256, 0, stream>>>(cnt, partial, N);
  k_scan3lb<<<nbS, 256, 0, stream>>>(cnt, partial, rowptr, cursor, N);
  // K5: scatter + GEMM1 (independent)
  k_scatgemm<<<nScat + nblk * 6, 256, 0, stream>>>(ei, cursor, ssrc, E, NS, nScat,
                                                   XF, W1F, B1P, XLG, XR1, RE1, N, nblk);
  // K6: layer-1 fused
  k_gat1<<<(N + 3) / 4, 256, 0, stream>>>(XLG, XR1, RE1, at6, at4, bias1, ln1g, ln1b,
                                          rowptr, ssrc, HF, N);
  // K7: GEMM2
  k_mfma2<<<nblk, 256, 0, stream>>>(HF, W2F, B2P, XG2, X2R, X2E, X2S, N);
  // K8: layer-2 fused + output GEMV
  k_gat2<<<(N + 15) / 16, 256, 0, stream>>>(XG2, X2R, X2E, X2S, at2E, bias2, ln2g, ln2b,
                                            rowptr, ssrc, outW, outb, out, N);
}